// Round 14
// baseline (101.389 us; speedup 1.0000x reference)
//
#include <hip/hip_runtime.h>

#define S_LEN 2048
#define NHEADS 14
#define NKVH 2
#define HDIM 64
#define HID 896
#define NQKV 1152
#define NCHUNK 40   // per bh: sum over 16 q-blocks(128 rows) of ceil(128*(qt+1)/512)

typedef __bf16 bf16;
typedef __bf16 bf16x4 __attribute__((ext_vector_type(4)));
typedef __bf16 bf16x8 __attribute__((ext_vector_type(8)));
typedef float f32x4 __attribute__((ext_vector_type(4)));
typedef unsigned int u32x4 __attribute__((ext_vector_type(4)));

__device__ inline f32x4 mfma16(bf16x8 a, bf16x8 b, f32x4 c) {
  return __builtin_amdgcn_mfma_f32_16x16x32_bf16(a, b, c, 0, 0, 0);
}

__device__ inline void gload_lds16(const bf16* g, bf16* l) {
  __builtin_amdgcn_global_load_lds(
      (const __attribute__((address_space(1))) void*)g,
      (__attribute__((address_space(3))) void*)l, 16, 0, 0);
}
__device__ inline void gload_lds16b(const void* g, void* l) {
  __builtin_amdgcn_global_load_lds(
      (const __attribute__((address_space(1))) void*)g,
      (__attribute__((address_space(3))) void*)l, 16, 0, 0);
}

__device__ inline unsigned cvtpk(float lo, float hi) {
  unsigned r;
  asm("v_cvt_pk_bf16_f32 %0, %1, %2" : "=v"(r) : "v"(lo), "v"(hi));
  return r;
}

// chunk index c (0..39) -> (q-block qt 0..15, chunk-within ch); nch(qt)=(qt>>2)+1
__device__ inline void chunk_map(int c, int& qt, int& ch) {
  if (c < 4)       { qt = c;                ch = 0; }
  else if (c < 12) { qt = 4 + ((c - 4) >> 1); ch = (c - 4) & 1; }
  else if (c < 24) { int d = c - 12; qt = 8 + d / 3; ch = d % 3; }
  else             { int d = c - 24; qt = 12 + (d >> 2); ch = d & 3; }
}

// chunks sorted by tile-length descending (28 eights, 4 sixes, 4 fours, 4 twos):
// per-CU length-sums equalize (snake-LPT) while keeping bh-major locality.
__device__ const int chunk_order[NCHUNK] = {
  36, 37, 38, 39, 32, 33, 34, 28, 29, 30, 24, 25, 26, 21, 22, 23,
  18, 19, 15, 16, 12, 13, 10, 11, 8, 6, 4, 3,
  35, 20, 9, 2,   // sixes
  31, 17, 7, 1,   // fours
  27, 14, 5, 0    // twos
};

// ---------------- fused prep: cast X, transpose-cast all W, pack bias, trig table ----------------
__global__ __launch_bounds__(256) void prep_kernel(
    const float* __restrict__ X, bf16* __restrict__ Xb,
    const float* __restrict__ Wq, const float* __restrict__ Wk,
    const float* __restrict__ Wv, const float* __restrict__ Wo,
    bf16* __restrict__ WqkvT, bf16* __restrict__ WoT,
    const float* __restrict__ bq, const float* __restrict__ bk,
    const float* __restrict__ bv, float* __restrict__ biasq,
    float* __restrict__ trig) {
  __shared__ float tile[32][33];
  int blk = blockIdx.x;
  int tid = threadIdx.x;
  if (blk < 3584) {
    int i = blk * 256 + tid;
    if (i < 917504) {
      float4 v = reinterpret_cast<const float4*>(X)[i];
      bf16x4 o;
      o[0] = (bf16)v.x; o[1] = (bf16)v.y; o[2] = (bf16)v.z; o[3] = (bf16)v.w;
      reinterpret_cast<bf16x4*>(Xb)[i] = o;
    }
    return;
  }
  if (blk < 5376) {
    int t = blk - 3584;
    const float* W; bf16* dst; int N, bx, by;
    if (t < 784)       { W = Wq; dst = WqkvT;                      N = 896; bx = t % 28;          by = t / 28; }
    else if (t < 896)  { int u = t - 784;  W = Wk; dst = WqkvT + (size_t)896 * 896;  N = 128; bx = u % 4; by = u / 4; }
    else if (t < 1008) { int u = t - 896;  W = Wv; dst = WqkvT + (size_t)1024 * 896; N = 128; bx = u % 4; by = u / 4; }
    else               { int u = t - 1008; W = Wo; dst = WoT;      N = 896; bx = u % 28;          by = u / 28; }
    int n0 = bx * 32, k0 = by * 32;
    int tx = tid & 31, ty = tid >> 5;  // 32 x 8
#pragma unroll
    for (int j = 0; j < 32; j += 8)
      tile[ty + j][tx] = W[(size_t)(k0 + ty + j) * N + n0 + tx];
    __syncthreads();
#pragma unroll
    for (int j = 0; j < 32; j += 8)
      dst[(size_t)(n0 + ty + j) * HID + k0 + tx] = (bf16)tile[tx][ty + j];
    return;
  }
  if (blk < 5381) {
    int i = (blk - 5376) * 256 + tid;
    if (i < 896) biasq[i] = bq[i];
    else if (i < 1024) biasq[i] = bk[i - 896];
    else if (i < 1152) biasq[i] = bv[i - 1024];
    return;
  }
  // trig table: [2048][64] = cos at [s][d], sin at [s][32+d], d=0..31
  {
    int ti = blk - 5381;                 // 0..255
    int s = ti * 8 + (tid >> 5);
    int d = tid & 31;
    float inv = expf(-(float)d * (13.815510557964274f / 32.0f));  // 1e6^(-d/32)
    float a = (float)s * inv;
    float c, si;
    sincosf(a, &si, &c);
    trig[(size_t)s * 64 + d] = c;
    trig[(size_t)s * 64 + 32 + d] = si;
  }
}

// ---------------- GEMM1 fused with RoPE + Q/K/V layout ----------------
__global__ __launch_bounds__(256) void gemm_qkv_kernel(const bf16* __restrict__ A,
                                                       const bf16* __restrict__ Bt,
                                                       const float* __restrict__ bias,
                                                       const float* __restrict__ trig,
                                                       bf16* __restrict__ Qb,
                                                       bf16* __restrict__ Kb,
                                                       bf16* __restrict__ Vt) {
  __shared__ __align__(16) char smem[33280];
  bf16* As = (bf16*)smem;              // [2][128][32] = 16384 B
  bf16* Bs = (bf16*)(smem + 16384);    // [2][64][32]  =  8192 B
  float* tileO = (float*)smem;         // [128][65] f32 = 33280 B (aliases As/Bs, used after loop)
  const int K = 896;
  int n0 = blockIdx.x * 64, m0 = blockIdx.y * 128;
  int tid = threadIdx.x;
  int wid = tid >> 6, lane = tid & 63;
  int lr = lane & 15, lh = lane >> 4;
  int wr = wid >> 1, wc = wid & 1;
  f32x4 acc[4][2] = {};

  auto stage = [&](int buf, int k0) {
#pragma unroll
    for (int i = 0; i < 2; ++i) {
      int seg = i * 4 + wid;
      int idx = seg * 512 + lane * 8;
      int r = idx >> 5, c = idx & 31;
      gload_lds16(A + (size_t)(m0 + r) * K + k0 + c, As + buf * 4096 + seg * 512);
    }
    {
      int idx = wid * 512 + lane * 8;
      int r = idx >> 5, c = idx & 31;
      gload_lds16(Bt + (size_t)(n0 + r) * K + k0 + c, Bs + buf * 2048 + wid * 512);
    }
  };

  stage(0, 0);
  __syncthreads();
  int nk = K >> 5;
  int cur = 0;
  for (int t = 0; t < nk; ++t) {
    if (t + 1 < nk) stage(cur ^ 1, (t + 1) << 5);
    bf16x8 am[4], bn[2];
#pragma unroll
    for (int mf = 0; mf < 4; ++mf)
      am[mf] = *reinterpret_cast<const bf16x8*>(As + cur * 4096 + (wr * 64 + mf * 16 + lr) * 32 + lh * 8);
#pragma unroll
    for (int nf = 0; nf < 2; ++nf)
      bn[nf] = *reinterpret_cast<const bf16x8*>(Bs + cur * 2048 + (wc * 32 + nf * 16 + lr) * 32 + lh * 8);
    __builtin_amdgcn_s_setprio(1);
#pragma unroll
    for (int mf = 0; mf < 4; ++mf)
#pragma unroll
      for (int nf = 0; nf < 2; ++nf)
        acc[mf][nf] = mfma16(am[mf], bn[nf], acc[mf][nf]);
    __builtin_amdgcn_s_setprio(0);
    __syncthreads();   // also makes As/Bs dead after the last iteration
    cur ^= 1;
  }

  // ---- store acc (+bias) to LDS f32 tile ----
#pragma unroll
  for (int nf = 0; nf < 2; ++nf) {
    int col = wc * 32 + nf * 16 + lr;
    float bb = bias[n0 + col];
#pragma unroll
    for (int mf = 0; mf < 4; ++mf) {
      int row0 = wr * 64 + mf * 16 + lh * 4;
#pragma unroll
      for (int j = 0; j < 4; ++j)
        tileO[(row0 + j) * 65 + col] = acc[mf][nf][j] + bb;
    }
  }
  __syncthreads();

  const float QSCALE = 0.125f * 1.44269504088896f;  // 1/sqrt(64) * log2(e)
  int b = blockIdx.y >> 4;
  int s0 = (blockIdx.y & 15) * 128;
  int bx = blockIdx.x;
  if (bx < 14) {
    // Q head: rope + scale, plain [b][h][s][64]
    int r2 = tid >> 1, half = tid & 1;
    int s = s0 + r2;
    const float* tr = trig + (size_t)s * 64;
    size_t base = ((size_t)(b * NHEADS + bx) * S_LEN + s) * HDIM;
    bf16x8 o1[2], o2[2];
#pragma unroll
    for (int v = 0; v < 2; ++v)
#pragma unroll
      for (int p = 0; p < 8; ++p) {
        int d = half * 16 + v * 8 + p;
        float c = tr[d], sn = tr[32 + d];
        float v1 = tileO[r2 * 65 + d], v2 = tileO[r2 * 65 + d + 32];
        o1[v][p] = (bf16)((v1 * c - v2 * sn) * QSCALE);
        o2[v][p] = (bf16)((v2 * c + v1 * sn) * QSCALE);
      }
    *(bf16x8*)(Qb + base + half * 16)      = o1[0];
    *(bf16x8*)(Qb + base + half * 16 + 8)  = o1[1];
    *(bf16x8*)(Qb + base + 32 + half * 16)     = o2[0];
    *(bf16x8*)(Qb + base + 32 + half * 16 + 8) = o2[1];
  } else if (bx < 16) {
    // K head: rope + XOR swizzle d ^ (((s&7)^((s>>3)&1))<<3)
    int kh = bx - 14;
    int r2 = tid >> 1, half = tid & 1;
    int s = s0 + r2;
    const float* tr = trig + (size_t)s * 64;
    int sw = (((s & 7) ^ ((s >> 3) & 1)) << 3);
    size_t base = ((size_t)(b * NKVH + kh) * S_LEN + s) * HDIM;
#pragma unroll
    for (int p = 0; p < 16; ++p) {
      int d = half * 16 + p;
      float c = tr[d], sn = tr[32 + d];
      float v1 = tileO[r2 * 65 + d], v2 = tileO[r2 * 65 + d + 32];
      Kb[base + (d ^ sw)]        = (bf16)(v1 * c - v2 * sn);
      Kb[base + ((d + 32) ^ sw)] = (bf16)(v2 * c + v1 * sn);
    }
  } else {
    // V head: transpose to [b][kv][64][S], col (s&63) ^ ((d&7)<<3)
    int kh = bx - 16;
    int d = tid & 63, seg = tid >> 6;
    size_t vbase = ((size_t)(b * NKVH + kh) * HDIM + d) * S_LEN;
    int c8 = (d & 7) << 3;
#pragma unroll
    for (int g = 0; g < 4; ++g) {
      int sl = seg * 32 + g * 8;   // aligned-8 s_local run
      bf16x8 w;
#pragma unroll
      for (int p = 0; p < 8; ++p)
        w[p] = (bf16)tileO[(sl + p) * 65 + d];
      int s = s0 + sl;
      int col = (s & ~63) | (((s & 63) ^ c8) & ~7);
      *(bf16x8*)(Vt + vbase + col) = w;
    }
  }
}

// ---------------- GEMM: C[M][N] = A[M][K](bf16) * Bt[N][K](bf16)^T (f32 out) ----------------
__global__ __launch_bounds__(256) void gemm_bt_kernel(const bf16* __restrict__ A,
                                                      const bf16* __restrict__ Bt,
                                                      float* __restrict__ C,
                                                      int M, int N, int K) {
  __shared__ __align__(16) bf16 As[2][128][32];
  __shared__ __align__(16) bf16 Bs[2][64][32];
  int n0 = blockIdx.x * 64, m0 = blockIdx.y * 128;
  int tid = threadIdx.x;
  int wid = tid >> 6, lane = tid & 63;
  int lr = lane & 15, lh = lane >> 4;
  int wr = wid >> 1, wc = wid & 1;
  f32x4 acc[4][2] = {};

  auto stage = [&](int buf, int k0) {
#pragma unroll
    for (int i = 0; i < 2; ++i) {
      int seg = i * 4 + wid;
      int idx = seg * 512 + lane * 8;
      int r = idx >> 5, c = idx & 31;
      gload_lds16(A + (size_t)(m0 + r) * K + k0 + c, &As[buf][0][0] + seg * 512);
    }
    {
      int idx = wid * 512 + lane * 8;
      int r = idx >> 5, c = idx & 31;
      gload_lds16(Bt + (size_t)(n0 + r) * K + k0 + c, &Bs[buf][0][0] + wid * 512);
    }
  };

  stage(0, 0);
  __syncthreads();
  int nk = K >> 5;
  int cur = 0;
  for (int t = 0; t < nk; ++t) {
    if (t + 1 < nk) stage(cur ^ 1, (t + 1) << 5);
    bf16x8 am[4], bn[2];
#pragma unroll
    for (int mf = 0; mf < 4; ++mf)
      am[mf] = *reinterpret_cast<const bf16x8*>(&As[cur][wr * 64 + mf * 16 + lr][lh * 8]);
#pragma unroll
    for (int nf = 0; nf < 2; ++nf)
      bn[nf] = *reinterpret_cast<const bf16x8*>(&Bs[cur][wc * 32 + nf * 16 + lr][lh * 8]);
    __builtin_amdgcn_s_setprio(1);
#pragma unroll
    for (int mf = 0; mf < 4; ++mf)
#pragma unroll
      for (int nf = 0; nf < 2; ++nf)
        acc[mf][nf] = mfma16(am[mf], bn[nf], acc[mf][nf]);
    __builtin_amdgcn_s_setprio(0);
    __syncthreads();
    cur ^= 1;
  }

#pragma unroll
  for (int nf = 0; nf < 2; ++nf) {
    int col = n0 + wc * 32 + nf * 16 + lr;
#pragma unroll
    for (int mf = 0; mf < 4; ++mf) {
      int row0 = m0 + wr * 64 + mf * 16 + lh * 4;
#pragma unroll
      for (int j = 0; j < 4; ++j)
        C[(size_t)(row0 + j) * N + col] = acc[mf][nf][j];
    }
  }
}

// ---------------- flash attention: shuffle-free steady-state softmax ----------------
// l is LANE-PARTIAL during the loop (each lane sums its own 16 k-slots); combined
// across the 4 lanes of each row once at the epilogue. Row-max reduce (2 shuffles)
// runs only when lane-local growth exceeds THR=8 (defer-max extended to the reduce).
// Opart: [28][40][128][64] bf16, Oml: [28][40][128][2] f32 (m, l in log2 domain)
__global__ __launch_bounds__(256, 4) void attn_kernel(const bf16* __restrict__ Qb,
                                                      const bf16* __restrict__ Kb,
                                                      const bf16* __restrict__ Vt,
                                                      bf16* __restrict__ Opart,
                                                      float* __restrict__ Oml,
                                                      bf16* __restrict__ Ob) {
  int blk = blockIdx.x;
  int c = chunk_order[blk % NCHUNK], bh = blk / NCHUNK;
  int qt, ch;
  chunk_map(c, qt, ch);
  int h = bh % NHEADS, b = bh / NHEADS;
  int q0 = qt * 128;
  int kv = h / 7;
  int kc0 = ch * 512;
  int kend = min(kc0 + 512, q0 + 128);
  int nt = (kend - kc0) >> 6;
  int tid = threadIdx.x, wid = tid >> 6, lane = tid & 63;
  int lr = lane & 15, lh = lane >> 4;
  int swk = (lr & 7) << 4;   // byte XOR for V LDS reads

  const bf16* Qp = Qb + ((size_t)(b * NHEADS + h) * S_LEN + q0 + wid * 32) * HDIM;
  const char* KpB = (const char*)(Kb + (size_t)(b * NKVH + kv) * S_LEN * HDIM);
  const char* VpB = (const char*)(Vt + (size_t)(b * NKVH + kv) * HDIM * S_LEN);

  __shared__ __align__(16) bf16 Ks[2][4096];
  __shared__ __align__(16) bf16 Vs[2][4096];

  bf16x8 aq[2][2];
#pragma unroll
  for (int f = 0; f < 2; ++f)
#pragma unroll
    for (int kk = 0; kk < 2; ++kk)
      aq[f][kk] = *reinterpret_cast<const bf16x8*>(
          Qp + (size_t)(f * 16 + lr) * HDIM + kk * 32 + lh * 8);

  float m[2] = {-3.0e38f, -3.0e38f}, l[2] = {0.f, 0.f};
  f32x4 o[2][4] = {};

  auto stage = [&](int buf, int kv0) {
#pragma unroll
    for (int i = 0; i < 2; ++i) {
      gload_lds16b(KpB + (size_t)kv0 * 128 + wid * 2048 + i * 1024 + lane * 16,
                   &Ks[buf][wid * 1024 + i * 512]);
      int d = wid * 16 + i * 8 + (lane >> 3);
      gload_lds16b(VpB + (size_t)d * (S_LEN * 2) + kv0 * 2 + (lane & 7) * 16,
                   &Vs[buf][wid * 1024 + i * 512]);
    }
  };

  stage(0, kc0);
  __syncthreads();

  int qf0 = q0 + wid * 32;
  int cur = 0;
  for (int t = 0; t < nt; ++t) {
    int kv0 = kc0 + (t << 6);
    // ---- swapped QK^T: sacc[f][nf][j] = S[q = qf0+f*16+lr][k = kv0+g(nf, lh*4+j)] ----
    const char* KsB = (const char*)&Ks[cur][0];
    f32x4 sacc[2][4] = {};
#pragma unroll
    for (int nf = 0; nf < 4; ++nf) {
      int rowk = 8 * (lr >> 2) + (lr & 3) + ((nf & 1) << 2) + ((nf >> 1) << 5);
      int rsw = (((rowk & 7) ^ ((rowk >> 3) & 1)) << 4);
#pragma unroll
      for (int kk = 0; kk < 2; ++kk) {
        bf16x8 kb = *(const bf16x8*)(KsB + rowk * 128 + ((kk * 64 + lh * 16) ^ rsw));
        sacc[0][nf] = mfma16(kb, aq[0][kk], sacc[0][nf]);
        sacc[1][nf] = mfma16(kb, aq[1][kk], sacc[1][nf]);
      }
    }
    if (t + 1 < nt) stage(cur ^ 1, kv0 + 64);

    // ---- mask (wave-uniform skip) + LANE-LOCAL max (no shuffles) ----
    float lmax[2];
#pragma unroll
    for (int f = 0; f < 2; ++f) {
      int qg = qf0 + f * 16 + lr;
      if (kv0 + 63 > qf0 + f * 16) {
#pragma unroll
        for (int nf = 0; nf < 4; ++nf) {
          int kb0 = kv0 + ((nf & 1) << 2) + ((nf >> 1) << 5) + (lh << 3);
#pragma unroll
          for (int j = 0; j < 4; ++j)
            if (kb0 + j > qg) sacc[f][nf][j] = -3.0e38f;
        }
      }
      f32x4 m01, m23;
#pragma unroll
      for (int j = 0; j < 4; ++j) {
        m01[j] = fmaxf(sacc[f][0][j], sacc[f][1][j]);
        m23[j] = fmaxf(sacc[f][2][j], sacc[f][3][j]);
      }
      f32x4 m4;
#pragma unroll
      for (int j = 0; j < 4; ++j) m4[j] = fmaxf(m01[j], m23[j]);
      lmax[f] = fmaxf(fmaxf(m4[0], m4[1]), fmaxf(m4[2], m4[3]));
    }
    // ---- defer-max guard: cross-lane reduce + rescale only on growth > 8 ----
    float g = fmaxf(lmax[0] - m[0], lmax[1] - m[1]);
    if (!__all(g <= 8.0f)) {
#pragma unroll
      for (int f = 0; f < 2; ++f) {
        float mxl = fmaxf(lmax[f], __shfl_xor(lmax[f], 16));
        mxl = fmaxf(mxl, __shfl_xor(mxl, 32));
        float mn = fmaxf(m[f], mxl);
        float al = exp2f(m[f] - mn);
        m[f] = mn;
        l[f] *= al;
        f32x4 av;
#pragma unroll
        for (int j = 0; j < 4; ++j) av[j] = __shfl(al, (lh << 2) + j);
#pragma unroll
        for (int nf = 0; nf < 4; ++nf) o[f][nf] *= av;
      }
    }
    // ---- exp2 + LANE-PARTIAL sum (no shuffles) + in-register P pack ----
    bf16x8 pa[2][2];
#pragma unroll
    for (int f = 0; f < 2; ++f) {
      f32x4 rs4 = {0.f, 0.f, 0.f, 0.f};
#pragma unroll
      for (int nf = 0; nf < 4; ++nf) {
#pragma unroll
        for (int j = 0; j < 4; ++j)
          sacc[f][nf][j] = exp2f(sacc[f][nf][j] - m[f]);
        rs4 += sacc[f][nf];
      }
      l[f] += (rs4[0] + rs4[1]) + (rs4[2] + rs4[3]);   // lane-partial
#pragma unroll
      for (int kk = 0; kk < 2; ++kk) {
        u32x4 w;
        w[0] = cvtpk(sacc[f][2 * kk][0], sacc[f][2 * kk][1]);
        w[1] = cvtpk(sacc[f][2 * kk][2], sacc[f][2 * kk][3]);
        w[2] = cvtpk(sacc[f][2 * kk + 1][0], sacc[f][2 * kk + 1][1]);
        w[3] = cvtpk(sacc[f][2 * kk + 1][2], sacc[f][2 * kk + 1][3]);
        pa[f][kk] = __builtin_bit_cast(bf16x8, w);
      }
    }
    // ---- PV ----
    const char* VsB = (const char*)&Vs[cur][0];
#pragma unroll
    for (int nf = 0; nf < 4; ++nf) {
#pragma unroll
      for (int kk = 0; kk < 2; ++kk) {
        bf16x8 vb = *(const bf16x8*)(VsB + (nf * 16 + lr) * 128 + ((kk * 64 + lh * 16) ^ swk));
        o[0][nf] = mfma16(pa[0][kk], vb, o[0][nf]);
        o[1][nf] = mfma16(pa[1][kk], vb, o[1][nf]);
      }
    }
    __syncthreads();   // drains staging vmcnt + protects buffer flip
    cur ^= 1;
  }

  // complete the row-sums: combine the 4 lane-partials of each row (once per chunk)
#pragma unroll
  for (int f = 0; f < 2; ++f) {
    l[f] += __shfl_xor(l[f], 16);
    l[f] += __shfl_xor(l[f], 32);
  }

  if (qt < 4) {
    // single-chunk q-tile: write normalized output directly to Ob (skip combine).
    // l[f] is lane-local to q-row lr; o[f][nf][j] lives at row lh*4+j -> transpose.
#pragma unroll
    for (int f = 0; f < 2; ++f) {
      f32x4 inv4;
#pragma unroll
      for (int j = 0; j < 4; ++j)
        inv4[j] = 1.0f / __shfl(l[f], (lh << 2) + j);
#pragma unroll
      for (int nf = 0; nf < 4; ++nf) {
        int col = h * 64 + nf * 16 + lr;
#pragma unroll
        for (int j = 0; j < 4; ++j) {
          int rloc = wid * 32 + f * 16 + (lh << 2) + j;
          Ob[((size_t)(b * S_LEN) + q0 + rloc) * HID + col] = (bf16)(o[f][nf][j] * inv4[j]);
        }
      }
    }
    return;
  }

  // epilogue: write unnormalized partial O (bf16) + per-row (m, l)
  size_t pbase = ((size_t)bh * NCHUNK + c) * (128 * 64);
#pragma unroll
  for (int f = 0; f < 2; ++f)
#pragma unroll
    for (int nf = 0; nf < 4; ++nf) {
      int col = nf * 16 + lr;
#pragma unroll
      for (int j = 0; j < 4; ++j) {
        int rloc = wid * 32 + f * 16 + (lh << 2) + j;
        Opart[pbase + (size_t)rloc * 64 + col] = (bf16)o[f][nf][j];
      }
    }
  if (lane < 16) {
    size_t mbase = ((size_t)bh * NCHUNK + c) * 128;
#pragma unroll
    for (int f = 0; f < 2; ++f) {
      int rloc = wid * 32 + f * 16 + lane;
      Oml[(mbase + rloc) * 2]     = m[f];
      Oml[(mbase + rloc) * 2 + 1] = l[f];
    }
  }
}

// ---------------- combine partials (qt >= 4 only; m in log2 domain) ----------------
__global__ __launch_bounds__(256) void combine_kernel(const bf16* __restrict__ Opart,
                                                      const float* __restrict__ Oml,
                                                      bf16* __restrict__ Ob) {
  int blk = blockIdx.x;            // bh*12 + (qt-4)
  int qt = 4 + blk % 12, bh = blk / 12;
  int h = bh % NHEADS, b = bh / NHEADS;
  int a = qt >> 2, bb = qt & 3;
  int nch = a + 1;
  int coff = (a + 1) * (2 * a + bb);
  int t = threadIdx.x;
  int row = t >> 1, cg = t & 1;    // 32 cols per thread

  float M = -__builtin_inff();
  for (int i = 0; i < nch; ++i)
    M = fmaxf(M, Oml[(((size_t)bh * NCHUNK + coff + i) * 128 + row) * 2]);
  float L = 0.f;
  for (int i = 0; i < nch; ++i) {
    size_t mb = (((size_t)bh * NCHUNK + coff + i) * 128 + row) * 2;
    L += exp2f(Oml[mb] - M) * Oml[mb + 1];
  }
  float acc[32];
#pragma unroll
  for (int k = 0; k < 32; ++k) acc[k] = 0.f;
  for (int i = 0; i < nch; ++i) {
    size_t mb = (((size_t)bh * NCHUNK + coff + i) * 128 + row) * 2;
    float w = exp2f(Oml[mb] - M);
    const bf16* src = Opart + (((size_t)bh * NCHUNK + coff + i) * 128 + row) * 64 + cg * 32;
#pragma unroll
    for (int v = 0; v < 4; ++v) {
      bf16x8 x = *reinterpret_cast<const bf16x8*>(src + v * 8);
#pragma unroll
      for (int k = 0; k < 8; ++k) acc[v * 8 + k] += w * (float)x[k];
    }
  }
  float inv = 1.0f / L;
  bf16* dst = Ob + ((size_t)(b * S_LEN) + qt * 128 + row) * HID + h * 64 + cg * 32;
#pragma unroll
  for (int v = 0; v < 4; ++v) {
    bf16x8 r;
#pragma unroll
    for (int k = 0; k < 8; ++k) r[k] = (bf16)(acc[v * 8 + k] * inv);
    *reinterpret_cast<bf16x8*>(dst + v * 8) = r;
  }
}

// ---------------- launch ----------------
extern "C" void kernel_launch(void* const* d_in, const int* in_sizes, int n_in,
                              void* d_out, int out_size, void* d_ws, size_t ws_size,
                              hipStream_t stream) {
  (void)in_sizes; (void)n_in; (void)out_size; (void)ws_size;
  const float* X  = (const float*)d_in[0];
  const float* Wq = (const float*)d_in[2];
  const float* bq = (const float*)d_in[3];
  const float* Wk = (const float*)d_in[4];
  const float* bk = (const float*)d_in[5];
  const float* Wv = (const float*)d_in[6];
  const float* bv = (const float*)d_in[7];
  const float* Wo = (const float*)d_in[8];
  float* OUT = (float*)d_out;

  char* ws = (char*)d_ws;
  bf16*  Xb    = (bf16*)(ws);                 // 4096*896*2  = 7,340,032
  bf16*  WqkvT = (bf16*)(ws + 7340032);       // 1152*896*2  = 2,064,384
  bf16*  WoT   = (bf16*)(ws + 9404416);       // 896*896*2   = 1,605,632
  float* biasq = (float*)(ws + 11010048);     // 1152*4
  bf16*  Opart = (bf16*)(ws + 11014656);      // 28*40*128*64*2 = 18,350,080
  float* trig  = (float*)(ws + 29364736);     // 2048*64*4 = 524,288 (ends 29,889,024)
  bf16*  Qbuf  = (bf16*)(ws + 29889024);      // 4096*896*2
  bf16*  Kbuf  = (bf16*)(ws + 37229056);      // 2*2*2048*64*2
  bf16*  Vbuf  = (bf16*)(ws + 38277632);      // 2*2*64*2048*2  (ends 39,326,208)
  float* Oml   = (float*)(ws + 7340032);      // reuse WqkvT region after GEMM1 (1,146,880)
  bf16*  Obuf  = Xb;                          // reuse (Xb dead after GEMM1)

  prep_kernel<<<5637, 256, 0, stream>>>(X, Xb, Wq, Wk, Wv, Wo, WqkvT, WoT,
                                        bq, bk, bv, biasq, trig);
  gemm_qkv_kernel<<<dim3(18, 32), 256, 0, stream>>>(Xb, WqkvT, biasq, trig,
                                                    Qbuf, Kbuf, Vbuf);
  attn_kernel<<<28 * NCHUNK, 256, 0, stream>>>(Qbuf, Kbuf, Vbuf, Opart, Oml, Obuf);
  combine_kernel<<<28 * 12, 256, 0, stream>>>(Opart, Oml, Obuf);
  gemm_bt_kernel<<<dim3(14, 32), 256, 0, stream>>>(Obuf, WoT, OUT, 4096, 896, 896);
}

// Round 15
// 100.474 us; speedup vs baseline: 1.0091x; 1.0091x over previous
//
#include <hip/hip_runtime.h>

#define S_LEN 2048
#define NHEADS 14
#define NKVH 2
#define HDIM 64
#define HID 896
#define NQKV 1152
#define NCHUNK 40   // per bh: sum over 16 q-blocks(128 rows) of ceil(128*(qt+1)/512)

typedef __bf16 bf16;
typedef __bf16 bf16x4 __attribute__((ext_vector_type(4)));
typedef __bf16 bf16x8 __attribute__((ext_vector_type(8)));
typedef float f32x4 __attribute__((ext_vector_type(4)));
typedef unsigned int u32x4 __attribute__((ext_vector_type(4)));

__device__ inline f32x4 mfma16(bf16x8 a, bf16x8 b, f32x4 c) {
  return __builtin_amdgcn_mfma_f32_16x16x32_bf16(a, b, c, 0, 0, 0);
}

__device__ inline void gload_lds16(const bf16* g, bf16* l) {
  __builtin_amdgcn_global_load_lds(
      (const __attribute__((address_space(1))) void*)g,
      (__attribute__((address_space(3))) void*)l, 16, 0, 0);
}
__device__ inline void gload_lds16b(const void* g, void* l) {
  __builtin_amdgcn_global_load_lds(
      (const __attribute__((address_space(1))) void*)g,
      (__attribute__((address_space(3))) void*)l, 16, 0, 0);
}

__device__ inline unsigned cvtpk(float lo, float hi) {
  unsigned r;
  asm("v_cvt_pk_bf16_f32 %0, %1, %2" : "=v"(r) : "v"(lo), "v"(hi));
  return r;
}

// chunk index c (0..39) -> (q-block qt 0..15, chunk-within ch); nch(qt)=(qt>>2)+1
__device__ inline void chunk_map(int c, int& qt, int& ch) {
  if (c < 4)       { qt = c;                ch = 0; }
  else if (c < 12) { qt = 4 + ((c - 4) >> 1); ch = (c - 4) & 1; }
  else if (c < 24) { int d = c - 12; qt = 8 + d / 3; ch = d % 3; }
  else             { int d = c - 24; qt = 12 + (d >> 2); ch = d & 3; }
}

// chunks sorted by tile-length descending (28 eights, 4 sixes, 4 fours, 4 twos):
// per-CU length-sums equalize (snake-LPT) while keeping bh-major locality.
__device__ const int chunk_order[NCHUNK] = {
  36, 37, 38, 39, 32, 33, 34, 28, 29, 30, 24, 25, 26, 21, 22, 23,
  18, 19, 15, 16, 12, 13, 10, 11, 8, 6, 4, 3,
  35, 20, 9, 2,   // sixes
  31, 17, 7, 1,   // fours
  27, 14, 5, 0    // twos
};

// ---------------- fused prep: cast X, transpose-cast all W, pack bias, trig table ----------------
__global__ __launch_bounds__(256) void prep_kernel(
    const float* __restrict__ X, bf16* __restrict__ Xb,
    const float* __restrict__ Wq, const float* __restrict__ Wk,
    const float* __restrict__ Wv, const float* __restrict__ Wo,
    bf16* __restrict__ WqkvT, bf16* __restrict__ WoT,
    const float* __restrict__ bq, const float* __restrict__ bk,
    const float* __restrict__ bv, float* __restrict__ biasq,
    float* __restrict__ trig) {
  __shared__ float tile[32][33];
  int blk = blockIdx.x;
  int tid = threadIdx.x;
  if (blk < 3584) {
    int i = blk * 256 + tid;
    if (i < 917504) {
      float4 v = reinterpret_cast<const float4*>(X)[i];
      bf16x4 o;
      o[0] = (bf16)v.x; o[1] = (bf16)v.y; o[2] = (bf16)v.z; o[3] = (bf16)v.w;
      reinterpret_cast<bf16x4*>(Xb)[i] = o;
    }
    return;
  }
  if (blk < 5376) {
    int t = blk - 3584;
    const float* W; bf16* dst; int N, bx, by;
    if (t < 784)       { W = Wq; dst = WqkvT;                      N = 896; bx = t % 28;          by = t / 28; }
    else if (t < 896)  { int u = t - 784;  W = Wk; dst = WqkvT + (size_t)896 * 896;  N = 128; bx = u % 4; by = u / 4; }
    else if (t < 1008) { int u = t - 896;  W = Wv; dst = WqkvT + (size_t)1024 * 896; N = 128; bx = u % 4; by = u / 4; }
    else               { int u = t - 1008; W = Wo; dst = WoT;      N = 896; bx = u % 28;          by = u / 28; }
    int n0 = bx * 32, k0 = by * 32;
    int tx = tid & 31, ty = tid >> 5;  // 32 x 8
#pragma unroll
    for (int j = 0; j < 32; j += 8)
      tile[ty + j][tx] = W[(size_t)(k0 + ty + j) * N + n0 + tx];
    __syncthreads();
#pragma unroll
    for (int j = 0; j < 32; j += 8)
      dst[(size_t)(n0 + ty + j) * HID + k0 + tx] = (bf16)tile[tx][ty + j];
    return;
  }
  if (blk < 5381) {
    int i = (blk - 5376) * 256 + tid;
    if (i < 896) biasq[i] = bq[i];
    else if (i < 1024) biasq[i] = bk[i - 896];
    else if (i < 1152) biasq[i] = bv[i - 1024];
    return;
  }
  // trig table: [2048][64] = cos at [s][d], sin at [s][32+d], d=0..31
  {
    int ti = blk - 5381;                 // 0..255
    int s = ti * 8 + (tid >> 5);
    int d = tid & 31;
    float inv = expf(-(float)d * (13.815510557964274f / 32.0f));  // 1e6^(-d/32)
    float a = (float)s * inv;
    float c, si;
    sincosf(a, &si, &c);
    trig[(size_t)s * 64 + d] = c;
    trig[(size_t)s * 64 + 32 + d] = si;
  }
}

// ---------------- GEMM1 fused with RoPE + Q/K/V layout (T2-swizzled LDS tiles) ----------------
// LDS layout: linear dest; global src chunk pre-permuted so LDS row r, 16B-pos p holds
// global chunk p ^ ((r>>1)&3); fragment reads XOR the same term -> conflict-free b128.
__global__ __launch_bounds__(256) void gemm_qkv_kernel(const bf16* __restrict__ A,
                                                       const bf16* __restrict__ Bt,
                                                       const float* __restrict__ bias,
                                                       const float* __restrict__ trig,
                                                       bf16* __restrict__ Qb,
                                                       bf16* __restrict__ Kb,
                                                       bf16* __restrict__ Vt) {
  __shared__ __align__(16) char smem[33280];
  bf16* As = (bf16*)smem;              // [2][128][32] = 16384 B
  bf16* Bs = (bf16*)(smem + 16384);    // [2][64][32]  =  8192 B
  float* tileO = (float*)smem;         // [128][65] f32 = 33280 B (aliases As/Bs, used after loop)
  const int K = 896;
  int n0 = blockIdx.x * 64, m0 = blockIdx.y * 128;
  int tid = threadIdx.x;
  int wid = tid >> 6, lane = tid & 63;
  int lr = lane & 15, lh = lane >> 4;
  int wr = wid >> 1, wc = wid & 1;
  int swz = ((lane & 3) ^ ((lane >> 3) & 3)) * 8;   // pre-swizzled global chunk (elems)
  int csw = (lr >> 1) & 3;                          // read-side XOR (16B units)
  f32x4 acc[4][2] = {};

  auto stage = [&](int buf, int k0) {
#pragma unroll
    for (int i = 0; i < 2; ++i) {
      int seg = i * 4 + wid;
      int r = seg * 16 + (lane >> 2);
      gload_lds16(A + (size_t)(m0 + r) * K + k0 + swz, As + buf * 4096 + seg * 512);
    }
    {
      int r = wid * 16 + (lane >> 2);
      gload_lds16(Bt + (size_t)(n0 + r) * K + k0 + swz, Bs + buf * 2048 + wid * 512);
    }
  };

  stage(0, 0);
  __syncthreads();
  int nk = K >> 5;
  int cur = 0;
  for (int t = 0; t < nk; ++t) {
    if (t + 1 < nk) stage(cur ^ 1, (t + 1) << 5);
    bf16x8 am[4], bn[2];
#pragma unroll
    for (int mf = 0; mf < 4; ++mf)
      am[mf] = *reinterpret_cast<const bf16x8*>(
          (char*)(As + cur * 4096 + (wr * 64 + mf * 16 + lr) * 32) + ((lh ^ csw) * 16));
#pragma unroll
    for (int nf = 0; nf < 2; ++nf)
      bn[nf] = *reinterpret_cast<const bf16x8*>(
          (char*)(Bs + cur * 2048 + (wc * 32 + nf * 16 + lr) * 32) + ((lh ^ csw) * 16));
    __builtin_amdgcn_s_setprio(1);
#pragma unroll
    for (int mf = 0; mf < 4; ++mf)
#pragma unroll
      for (int nf = 0; nf < 2; ++nf)
        acc[mf][nf] = mfma16(am[mf], bn[nf], acc[mf][nf]);
    __builtin_amdgcn_s_setprio(0);
    __syncthreads();   // also makes As/Bs dead after the last iteration
    cur ^= 1;
  }

  // ---- store acc (+bias) to LDS f32 tile ----
#pragma unroll
  for (int nf = 0; nf < 2; ++nf) {
    int col = wc * 32 + nf * 16 + lr;
    float bb = bias[n0 + col];
#pragma unroll
    for (int mf = 0; mf < 4; ++mf) {
      int row0 = wr * 64 + mf * 16 + lh * 4;
#pragma unroll
      for (int j = 0; j < 4; ++j)
        tileO[(row0 + j) * 65 + col] = acc[mf][nf][j] + bb;
    }
  }
  __syncthreads();

  const float QSCALE = 0.125f * 1.44269504088896f;  // 1/sqrt(64) * log2(e)
  int b = blockIdx.y >> 4;
  int s0 = (blockIdx.y & 15) * 128;
  int bx = blockIdx.x;
  if (bx < 14) {
    // Q head: rope + scale, plain [b][h][s][64]
    int r2 = tid >> 1, half = tid & 1;
    int s = s0 + r2;
    const float* tr = trig + (size_t)s * 64;
    size_t base = ((size_t)(b * NHEADS + bx) * S_LEN + s) * HDIM;
    bf16x8 o1[2], o2[2];
#pragma unroll
    for (int v = 0; v < 2; ++v)
#pragma unroll
      for (int p = 0; p < 8; ++p) {
        int d = half * 16 + v * 8 + p;
        float c = tr[d], sn = tr[32 + d];
        float v1 = tileO[r2 * 65 + d], v2 = tileO[r2 * 65 + d + 32];
        o1[v][p] = (bf16)((v1 * c - v2 * sn) * QSCALE);
        o2[v][p] = (bf16)((v2 * c + v1 * sn) * QSCALE);
      }
    *(bf16x8*)(Qb + base + half * 16)      = o1[0];
    *(bf16x8*)(Qb + base + half * 16 + 8)  = o1[1];
    *(bf16x8*)(Qb + base + 32 + half * 16)     = o2[0];
    *(bf16x8*)(Qb + base + 32 + half * 16 + 8) = o2[1];
  } else if (bx < 16) {
    // K head: rope + XOR swizzle d ^ (((s&7)^((s>>3)&1))<<3)
    int kh = bx - 14;
    int r2 = tid >> 1, half = tid & 1;
    int s = s0 + r2;
    const float* tr = trig + (size_t)s * 64;
    int sw = (((s & 7) ^ ((s >> 3) & 1)) << 3);
    size_t base = ((size_t)(b * NKVH + kh) * S_LEN + s) * HDIM;
#pragma unroll
    for (int p = 0; p < 16; ++p) {
      int d = half * 16 + p;
      float c = tr[d], sn = tr[32 + d];
      float v1 = tileO[r2 * 65 + d], v2 = tileO[r2 * 65 + d + 32];
      Kb[base + (d ^ sw)]        = (bf16)(v1 * c - v2 * sn);
      Kb[base + ((d + 32) ^ sw)] = (bf16)(v2 * c + v1 * sn);
    }
  } else {
    // V head: transpose to [b][kv][64][S], col (s&63) ^ ((d&7)<<3)
    int kh = bx - 16;
    int d = tid & 63, seg = tid >> 6;
    size_t vbase = ((size_t)(b * NKVH + kh) * HDIM + d) * S_LEN;
    int c8 = (d & 7) << 3;
#pragma unroll
    for (int g = 0; g < 4; ++g) {
      int sl = seg * 32 + g * 8;   // aligned-8 s_local run
      bf16x8 w;
#pragma unroll
      for (int p = 0; p < 8; ++p)
        w[p] = (bf16)tileO[(sl + p) * 65 + d];
      int s = s0 + sl;
      int col = (s & ~63) | (((s & 63) ^ c8) & ~7);
      *(bf16x8*)(Vt + vbase + col) = w;
    }
  }
}

// ---------------- GEMM: C[M][N] = A[M][K](bf16) * Bt[N][K](bf16)^T (f32 out, T2-swizzled) ----------------
__global__ __launch_bounds__(256) void gemm_bt_kernel(const bf16* __restrict__ A,
                                                      const bf16* __restrict__ Bt,
                                                      float* __restrict__ C,
                                                      int M, int N, int K) {
  __shared__ __align__(16) bf16 As[2][128][32];
  __shared__ __align__(16) bf16 Bs[2][64][32];
  int n0 = blockIdx.x * 64, m0 = blockIdx.y * 128;
  int tid = threadIdx.x;
  int wid = tid >> 6, lane = tid & 63;
  int lr = lane & 15, lh = lane >> 4;
  int wr = wid >> 1, wc = wid & 1;
  int swz = ((lane & 3) ^ ((lane >> 3) & 3)) * 8;   // pre-swizzled global chunk (elems)
  int csw = (lr >> 1) & 3;                          // read-side XOR (16B units)
  f32x4 acc[4][2] = {};

  auto stage = [&](int buf, int k0) {
#pragma unroll
    for (int i = 0; i < 2; ++i) {
      int seg = i * 4 + wid;
      int r = seg * 16 + (lane >> 2);
      gload_lds16(A + (size_t)(m0 + r) * K + k0 + swz, &As[buf][0][0] + seg * 512);
    }
    {
      int r = wid * 16 + (lane >> 2);
      gload_lds16(Bt + (size_t)(n0 + r) * K + k0 + swz, &Bs[buf][0][0] + wid * 512);
    }
  };

  stage(0, 0);
  __syncthreads();
  int nk = K >> 5;
  int cur = 0;
  for (int t = 0; t < nk; ++t) {
    if (t + 1 < nk) stage(cur ^ 1, (t + 1) << 5);
    bf16x8 am[4], bn[2];
#pragma unroll
    for (int mf = 0; mf < 4; ++mf)
      am[mf] = *reinterpret_cast<const bf16x8*>(
          (char*)&As[cur][wr * 64 + mf * 16 + lr][0] + ((lh ^ csw) * 16));
#pragma unroll
    for (int nf = 0; nf < 2; ++nf)
      bn[nf] = *reinterpret_cast<const bf16x8*>(
          (char*)&Bs[cur][wc * 32 + nf * 16 + lr][0] + ((lh ^ csw) * 16));
    __builtin_amdgcn_s_setprio(1);
#pragma unroll
    for (int mf = 0; mf < 4; ++mf)
#pragma unroll
      for (int nf = 0; nf < 2; ++nf)
        acc[mf][nf] = mfma16(am[mf], bn[nf], acc[mf][nf]);
    __builtin_amdgcn_s_setprio(0);
    __syncthreads();
    cur ^= 1;
  }

#pragma unroll
  for (int nf = 0; nf < 2; ++nf) {
    int col = n0 + wc * 32 + nf * 16 + lr;
#pragma unroll
    for (int mf = 0; mf < 4; ++mf) {
      int row0 = m0 + wr * 64 + mf * 16 + lh * 4;
#pragma unroll
      for (int j = 0; j < 4; ++j)
        C[(size_t)(row0 + j) * N + col] = acc[mf][nf][j];
    }
  }
}

// ---------------- flash attention: shuffle-free steady-state softmax ----------------
// Opart: [28][40][128][64] bf16, Oml: [28][40][128][2] f32 (m, l in log2 domain)
__global__ __launch_bounds__(256, 4) void attn_kernel(const bf16* __restrict__ Qb,
                                                      const bf16* __restrict__ Kb,
                                                      const bf16* __restrict__ Vt,
                                                      bf16* __restrict__ Opart,
                                                      float* __restrict__ Oml,
                                                      bf16* __restrict__ Ob) {
  int blk = blockIdx.x;
  int c = chunk_order[blk % NCHUNK], bh = blk / NCHUNK;
  int qt, ch;
  chunk_map(c, qt, ch);
  int h = bh % NHEADS, b = bh / NHEADS;
  int q0 = qt * 128;
  int kv = h / 7;
  int kc0 = ch * 512;
  int kend = min(kc0 + 512, q0 + 128);
  int nt = (kend - kc0) >> 6;
  int tid = threadIdx.x, wid = tid >> 6, lane = tid & 63;
  int lr = lane & 15, lh = lane >> 4;
  int swk = (lr & 7) << 4;   // byte XOR for V LDS reads

  const bf16* Qp = Qb + ((size_t)(b * NHEADS + h) * S_LEN + q0 + wid * 32) * HDIM;
  const char* KpB = (const char*)(Kb + (size_t)(b * NKVH + kv) * S_LEN * HDIM);
  const char* VpB = (const char*)(Vt + (size_t)(b * NKVH + kv) * HDIM * S_LEN);

  __shared__ __align__(16) bf16 Ks[2][4096];
  __shared__ __align__(16) bf16 Vs[2][4096];

  bf16x8 aq[2][2];
#pragma unroll
  for (int f = 0; f < 2; ++f)
#pragma unroll
    for (int kk = 0; kk < 2; ++kk)
      aq[f][kk] = *reinterpret_cast<const bf16x8*>(
          Qp + (size_t)(f * 16 + lr) * HDIM + kk * 32 + lh * 8);

  float m[2] = {-3.0e38f, -3.0e38f}, l[2] = {0.f, 0.f};
  f32x4 o[2][4] = {};

  auto stage = [&](int buf, int kv0) {
#pragma unroll
    for (int i = 0; i < 2; ++i) {
      gload_lds16b(KpB + (size_t)kv0 * 128 + wid * 2048 + i * 1024 + lane * 16,
                   &Ks[buf][wid * 1024 + i * 512]);
      int d = wid * 16 + i * 8 + (lane >> 3);
      gload_lds16b(VpB + (size_t)d * (S_LEN * 2) + kv0 * 2 + (lane & 7) * 16,
                   &Vs[buf][wid * 1024 + i * 512]);
    }
  };

  stage(0, kc0);
  __syncthreads();

  int qf0 = q0 + wid * 32;
  int cur = 0;
  for (int t = 0; t < nt; ++t) {
    int kv0 = kc0 + (t << 6);
    // ---- swapped QK^T: sacc[f][nf][j] = S[q = qf0+f*16+lr][k = kv0+g(nf, lh*4+j)] ----
    const char* KsB = (const char*)&Ks[cur][0];
    f32x4 sacc[2][4] = {};
#pragma unroll
    for (int nf = 0; nf < 4; ++nf) {
      int rowk = 8 * (lr >> 2) + (lr & 3) + ((nf & 1) << 2) + ((nf >> 1) << 5);
      int rsw = (((rowk & 7) ^ ((rowk >> 3) & 1)) << 4);
#pragma unroll
      for (int kk = 0; kk < 2; ++kk) {
        bf16x8 kb = *(const bf16x8*)(KsB + rowk * 128 + ((kk * 64 + lh * 16) ^ rsw));
        sacc[0][nf] = mfma16(kb, aq[0][kk], sacc[0][nf]);
        sacc[1][nf] = mfma16(kb, aq[1][kk], sacc[1][nf]);
      }
    }
    if (t + 1 < nt) stage(cur ^ 1, kv0 + 64);

    // ---- mask (wave-uniform skip) + LANE-LOCAL max (no shuffles) ----
    float lmax[2];
#pragma unroll
    for (int f = 0; f < 2; ++f) {
      int qg = qf0 + f * 16 + lr;
      if (kv0 + 63 > qf0 + f * 16) {
#pragma unroll
        for (int nf = 0; nf < 4; ++nf) {
          int kb0 = kv0 + ((nf & 1) << 2) + ((nf >> 1) << 5) + (lh << 3);
#pragma unroll
          for (int j = 0; j < 4; ++j)
            if (kb0 + j > qg) sacc[f][nf][j] = -3.0e38f;
        }
      }
      f32x4 m01, m23;
#pragma unroll
      for (int j = 0; j < 4; ++j) {
        m01[j] = fmaxf(sacc[f][0][j], sacc[f][1][j]);
        m23[j] = fmaxf(sacc[f][2][j], sacc[f][3][j]);
      }
      f32x4 m4;
#pragma unroll
      for (int j = 0; j < 4; ++j) m4[j] = fmaxf(m01[j], m23[j]);
      lmax[f] = fmaxf(fmaxf(m4[0], m4[1]), fmaxf(m4[2], m4[3]));
    }
    // ---- defer-max guard: cross-lane reduce + rescale only on growth > 8 ----
    float g = fmaxf(lmax[0] - m[0], lmax[1] - m[1]);
    if (!__all(g <= 8.0f)) {
#pragma unroll
      for (int f = 0; f < 2; ++f) {
        float mxl = fmaxf(lmax[f], __shfl_xor(lmax[f], 16));
        mxl = fmaxf(mxl, __shfl_xor(mxl, 32));
        float mn = fmaxf(m[f], mxl);
        float al = exp2f(m[f] - mn);
        m[f] = mn;
        l[f] *= al;
        f32x4 av;
#pragma unroll
        for (int j = 0; j < 4; ++j) av[j] = __shfl(al, (lh << 2) + j);
#pragma unroll
        for (int nf = 0; nf < 4; ++nf) o[f][nf] *= av;
      }
    }
    // ---- exp2 + LANE-PARTIAL sum (no shuffles) + in-register P pack ----
    bf16x8 pa[2][2];
#pragma unroll
    for (int f = 0; f < 2; ++f) {
      f32x4 rs4 = {0.f, 0.f, 0.f, 0.f};
#pragma unroll
      for (int nf = 0; nf < 4; ++nf) {
#pragma unroll
        for (int j = 0; j < 4; ++j)
          sacc[f][nf][j] = exp2f(sacc[f][nf][j] - m[f]);
        rs4 += sacc[f][nf];
      }
      l[f] += (rs4[0] + rs4[1]) + (rs4[2] + rs4[3]);   // lane-partial
#pragma unroll
      for (int kk = 0; kk < 2; ++kk) {
        u32x4 w;
        w[0] = cvtpk(sacc[f][2 * kk][0], sacc[f][2 * kk][1]);
        w[1] = cvtpk(sacc[f][2 * kk][2], sacc[f][2 * kk][3]);
        w[2] = cvtpk(sacc[f][2 * kk + 1][0], sacc[f][2 * kk + 1][1]);
        w[3] = cvtpk(sacc[f][2 * kk + 1][2], sacc[f][2 * kk + 1][3]);
        pa[f][kk] = __builtin_bit_cast(bf16x8, w);
      }
    }
    // ---- PV ----
    const char* VsB = (const char*)&Vs[cur][0];
#pragma unroll
    for (int nf = 0; nf < 4; ++nf) {
#pragma unroll
      for (int kk = 0; kk < 2; ++kk) {
        bf16x8 vb = *(const bf16x8*)(VsB + (nf * 16 + lr) * 128 + ((kk * 64 + lh * 16) ^ swk));
        o[0][nf] = mfma16(pa[0][kk], vb, o[0][nf]);
        o[1][nf] = mfma16(pa[1][kk], vb, o[1][nf]);
      }
    }
    __syncthreads();   // drains staging vmcnt + protects buffer flip
    cur ^= 1;
  }

  // complete the row-sums: combine the 4 lane-partials of each row (once per chunk)
#pragma unroll
  for (int f = 0; f < 2; ++f) {
    l[f] += __shfl_xor(l[f], 16);
    l[f] += __shfl_xor(l[f], 32);
  }

  if (qt < 4) {
    // single-chunk q-tile: write normalized output directly to Ob (skip combine).
    // l[f] is lane-local to q-row lr; o[f][nf][j] lives at row lh*4+j -> transpose.
#pragma unroll
    for (int f = 0; f < 2; ++f) {
      f32x4 inv4;
#pragma unroll
      for (int j = 0; j < 4; ++j)
        inv4[j] = 1.0f / __shfl(l[f], (lh << 2) + j);
#pragma unroll
      for (int nf = 0; nf < 4; ++nf) {
        int col = h * 64 + nf * 16 + lr;
#pragma unroll
        for (int j = 0; j < 4; ++j) {
          int rloc = wid * 32 + f * 16 + (lh << 2) + j;
          Ob[((size_t)(b * S_LEN) + q0 + rloc) * HID + col] = (bf16)(o[f][nf][j] * inv4[j]);
        }
      }
    }
    return;
  }

  // epilogue: write unnormalized partial O (bf16) + per-row (m, l)
  size_t pbase = ((size_t)bh * NCHUNK + c) * (128 * 64);
#pragma unroll
  for (int f = 0; f < 2; ++f)
#pragma unroll
    for (int nf = 0; nf < 4; ++nf) {
      int col = nf * 16 + lr;
#pragma unroll
      for (int j = 0; j < 4; ++j) {
        int rloc = wid * 32 + f * 16 + (lh << 2) + j;
        Opart[pbase + (size_t)rloc * 64 + col] = (bf16)o[f][nf][j];
      }
    }
  if (lane < 16) {
    size_t mbase = ((size_t)bh * NCHUNK + c) * 128;
#pragma unroll
    for (int f = 0; f < 2; ++f) {
      int rloc = wid * 32 + f * 16 + lane;
      Oml[(mbase + rloc) * 2]     = m[f];
      Oml[(mbase + rloc) * 2 + 1] = l[f];
    }
  }
}

// ---------------- combine partials (qt >= 4 only; m in log2 domain) ----------------
__global__ __launch_bounds__(256) void combine_kernel(const bf16* __restrict__ Opart,
                                                      const float* __restrict__ Oml,
                                                      bf16* __restrict__ Ob) {
  int blk = blockIdx.x;            // bh*12 + (qt-4)
  int qt = 4 + blk % 12, bh = blk / 12;
  int h = bh % NHEADS, b = bh / NHEADS;
  int a = qt >> 2, bb = qt & 3;
  int nch = a + 1;
  int coff = (a + 1) * (2 * a + bb);
  int t = threadIdx.x;
  int row = t >> 1, cg = t & 1;    // 32 cols per thread

  float M = -__builtin_inff();
  for (int i = 0; i < nch; ++i)
    M = fmaxf(M, Oml[(((size_t)bh * NCHUNK + coff + i) * 128 + row) * 2]);
  float L = 0.f;
  for (int i = 0; i < nch; ++i) {
    size_t mb = (((size_t)bh * NCHUNK + coff + i) * 128 + row) * 2;
    L += exp2f(Oml[mb] - M) * Oml[mb + 1];
  }
  float acc[32];
#pragma unroll
  for (int k = 0; k < 32; ++k) acc[k] = 0.f;
  for (int i = 0; i < nch; ++i) {
    size_t mb = (((size_t)bh * NCHUNK + coff + i) * 128 + row) * 2;
    float w = exp2f(Oml[mb] - M);
    const bf16* src = Opart + (((size_t)bh * NCHUNK + coff + i) * 128 + row) * 64 + cg * 32;
#pragma unroll
    for (int v = 0; v < 4; ++v) {
      bf16x8 x = *reinterpret_cast<const bf16x8*>(src + v * 8);
#pragma unroll
      for (int k = 0; k < 8; ++k) acc[v * 8 + k] += w * (float)x[k];
    }
  }
  float inv = 1.0f / L;
  bf16* dst = Ob + ((size_t)(b * S_LEN) + qt * 128 + row) * HID + h * 64 + cg * 32;
#pragma unroll
  for (int v = 0; v < 4; ++v) {
    bf16x8 r;
#pragma unroll
    for (int k = 0; k < 8; ++k) r[k] = (bf16)(acc[v * 8 + k] * inv);
    *reinterpret_cast<bf16x8*>(dst + v * 8) = r;
  }
}

// ---------------- launch ----------------
extern "C" void kernel_launch(void* const* d_in, const int* in_sizes, int n_in,
                              void* d_out, int out_size, void* d_ws, size_t ws_size,
                              hipStream_t stream) {
  (void)in_sizes; (void)n_in; (void)out_size; (void)ws_size;
  const float* X  = (const float*)d_in[0];
  const float* Wq = (const float*)d_in[2];
  const float* bq = (const float*)d_in[3];
  const float* Wk = (const float*)d_in[4];
  const float* bk = (const float*)d_in[5];
  const float* Wv = (const float*)d_in[6];
  const float* bv = (const float*)d_in[7];
  const float* Wo = (const float*)d_in[8];
  float* OUT = (float*)d_out;

  char* ws = (char*)d_ws;
  bf16*  Xb    = (bf16*)(ws);                 // 4096*896*2  = 7,340,032
  bf16*  WqkvT = (bf16*)(ws + 7340032);       // 1152*896*2  = 2,064,384
  bf16*  WoT   = (bf16*)(ws + 9404416);       // 896*896*2   = 1,605,632
  float* biasq = (float*)(ws + 11010048);     // 1152*4
  bf16*  Opart = (bf16*)(ws + 11014656);      // 28*40*128*64*2 = 18,350,080
  float* trig  = (float*)(ws + 29364736);     // 2048*64*4 = 524,288 (ends 29,889,024)
  bf16*  Qbuf  = (bf16*)(ws + 29889024);      // 4096*896*2
  bf16*  Kbuf  = (bf16*)(ws + 37229056);      // 2*2*2048*64*2
  bf16*  Vbuf  = (bf16*)(ws + 38277632);      // 2*2*64*2048*2  (ends 39,326,208)
  float* Oml   = (float*)(ws + 7340032);      // reuse WqkvT region after GEMM1 (1,146,880)
  bf16*  Obuf  = Xb;                          // reuse (Xb dead after GEMM1)

  prep_kernel<<<5637, 256, 0, stream>>>(X, Xb, Wq, Wk, Wv, Wo, WqkvT, WoT,
                                        bq, bk, bv, biasq, trig);
  gemm_qkv_kernel<<<dim3(18, 32), 256, 0, stream>>>(Xb, WqkvT, biasq, trig,
                                                    Qbuf, Kbuf, Vbuf);
  attn_kernel<<<28 * NCHUNK, 256, 0, stream>>>(Qbuf, Kbuf, Vbuf, Opart, Oml, Obuf);
  combine_kernel<<<28 * 12, 256, 0, stream>>>(Opart, Oml, Obuf);
  gemm_bt_kernel<<<dim3(14, 32), 256, 0, stream>>>(Obuf, WoT, OUT, 4096, 896, 896);
}

// Round 16
// 97.001 us; speedup vs baseline: 1.0452x; 1.0358x over previous
//
#include <hip/hip_runtime.h>

#define S_LEN 2048
#define NHEADS 14
#define NKVH 2
#define HDIM 64
#define HID 896
#define NQKV 1152
#define NCHUNK 40   // per bh: sum over 16 q-blocks(128 rows) of ceil(128*(qt+1)/512)

typedef __bf16 bf16;
typedef __bf16 bf16x4 __attribute__((ext_vector_type(4)));
typedef __bf16 bf16x8 __attribute__((ext_vector_type(8)));
typedef float f32x4 __attribute__((ext_vector_type(4)));
typedef unsigned int u32x4 __attribute__((ext_vector_type(4)));

__device__ inline f32x4 mfma16(bf16x8 a, bf16x8 b, f32x4 c) {
  return __builtin_amdgcn_mfma_f32_16x16x32_bf16(a, b, c, 0, 0, 0);
}

__device__ inline void gload_lds16(const bf16* g, bf16* l) {
  __builtin_amdgcn_global_load_lds(
      (const __attribute__((address_space(1))) void*)g,
      (__attribute__((address_space(3))) void*)l, 16, 0, 0);
}
__device__ inline void gload_lds16b(const void* g, void* l) {
  __builtin_amdgcn_global_load_lds(
      (const __attribute__((address_space(1))) void*)g,
      (__attribute__((address_space(3))) void*)l, 16, 0, 0);
}

__device__ inline unsigned cvtpk(float lo, float hi) {
  unsigned r;
  asm("v_cvt_pk_bf16_f32 %0, %1, %2" : "=v"(r) : "v"(lo), "v"(hi));
  return r;
}

// chunk index c (0..39) -> (q-block qt 0..15, chunk-within ch); nch(qt)=(qt>>2)+1
__device__ inline void chunk_map(int c, int& qt, int& ch) {
  if (c < 4)       { qt = c;                ch = 0; }
  else if (c < 12) { qt = 4 + ((c - 4) >> 1); ch = (c - 4) & 1; }
  else if (c < 24) { int d = c - 12; qt = 8 + d / 3; ch = d % 3; }
  else             { int d = c - 24; qt = 12 + (d >> 2); ch = d & 3; }
}

// chunks sorted by tile-length descending (28 eights, 4 sixes, 4 fours, 4 twos):
// per-CU length-sums equalize (snake-LPT) while keeping bh-major locality.
__device__ const int chunk_order[NCHUNK] = {
  36, 37, 38, 39, 32, 33, 34, 28, 29, 30, 24, 25, 26, 21, 22, 23,
  18, 19, 15, 16, 12, 13, 10, 11, 8, 6, 4, 3,
  35, 20, 9, 2,   // sixes
  31, 17, 7, 1,   // fours
  27, 14, 5, 0    // twos
};

// ---------------- fused prep: cast X, transpose-cast all W, pack bias, trig table ----------------
__global__ __launch_bounds__(256) void prep_kernel(
    const float* __restrict__ X, bf16* __restrict__ Xb,
    const float* __restrict__ Wq, const float* __restrict__ Wk,
    const float* __restrict__ Wv, const float* __restrict__ Wo,
    bf16* __restrict__ WqkvT, bf16* __restrict__ WoT,
    const float* __restrict__ bq, const float* __restrict__ bk,
    const float* __restrict__ bv, float* __restrict__ biasq,
    float* __restrict__ trig) {
  __shared__ float tile[32][33];
  int blk = blockIdx.x;
  int tid = threadIdx.x;
  if (blk < 3584) {
    int i = blk * 256 + tid;
    if (i < 917504) {
      float4 v = reinterpret_cast<const float4*>(X)[i];
      bf16x4 o;
      o[0] = (bf16)v.x; o[1] = (bf16)v.y; o[2] = (bf16)v.z; o[3] = (bf16)v.w;
      reinterpret_cast<bf16x4*>(Xb)[i] = o;
    }
    return;
  }
  if (blk < 5376) {
    int t = blk - 3584;
    const float* W; bf16* dst; int N, bx, by;
    if (t < 784)       { W = Wq; dst = WqkvT;                      N = 896; bx = t % 28;          by = t / 28; }
    else if (t < 896)  { int u = t - 784;  W = Wk; dst = WqkvT + (size_t)896 * 896;  N = 128; bx = u % 4; by = u / 4; }
    else if (t < 1008) { int u = t - 896;  W = Wv; dst = WqkvT + (size_t)1024 * 896; N = 128; bx = u % 4; by = u / 4; }
    else               { int u = t - 1008; W = Wo; dst = WoT;      N = 896; bx = u % 28;          by = u / 28; }
    int n0 = bx * 32, k0 = by * 32;
    int tx = tid & 31, ty = tid >> 5;  // 32 x 8
#pragma unroll
    for (int j = 0; j < 32; j += 8)
      tile[ty + j][tx] = W[(size_t)(k0 + ty + j) * N + n0 + tx];
    __syncthreads();
#pragma unroll
    for (int j = 0; j < 32; j += 8)
      dst[(size_t)(n0 + ty + j) * HID + k0 + tx] = (bf16)tile[tx][ty + j];
    return;
  }
  if (blk < 5381) {
    int i = (blk - 5376) * 256 + tid;
    if (i < 896) biasq[i] = bq[i];
    else if (i < 1024) biasq[i] = bk[i - 896];
    else if (i < 1152) biasq[i] = bv[i - 1024];
    return;
  }
  // trig table: [2048][64] = cos at [s][d], sin at [s][32+d], d=0..31
  {
    int ti = blk - 5381;                 // 0..255
    int s = ti * 8 + (tid >> 5);
    int d = tid & 31;
    float inv = expf(-(float)d * (13.815510557964274f / 32.0f));  // 1e6^(-d/32)
    float a = (float)s * inv;
    float c, si;
    sincosf(a, &si, &c);
    trig[(size_t)s * 64 + d] = c;
    trig[(size_t)s * 64 + 32 + d] = si;
  }
}

// ---------------- GEMM1 fused with RoPE + Q/K/V layout (BK=64, swizzled LDS) ----------------
// LDS: linear dest; source 16B-chunk pre-permuted chunk^=(row&7); reads XOR ((row&7)<<4).
__global__ __launch_bounds__(256) void gemm_qkv_kernel(const bf16* __restrict__ A,
                                                       const bf16* __restrict__ Bt,
                                                       const float* __restrict__ bias,
                                                       const float* __restrict__ trig,
                                                       bf16* __restrict__ Qb,
                                                       bf16* __restrict__ Kb,
                                                       bf16* __restrict__ Vt) {
  __shared__ __align__(16) char smem[49152];
  bf16* As = (bf16*)smem;              // [2][128][64] = 32768 B
  bf16* Bs = (bf16*)(smem + 32768);    // [2][64][64]  = 16384 B
  float* tileO = (float*)smem;         // [128][65] f32 = 33280 B (aliases, used after loop)
  const int K = 896;
  int n0 = blockIdx.x * 64, m0 = blockIdx.y * 128;
  int tid = threadIdx.x;
  int wid = tid >> 6, lane = tid & 63;
  int lr = lane & 15, lh = lane >> 4;
  int wr = wid >> 1, wc = wid & 1;
  int lrow8 = lane >> 3, lchk = lane & 7;   // staging: 8 rows x 8 chunks per segment
  f32x4 acc[4][2] = {};

  auto stage = [&](int buf, int k0) {
#pragma unroll
    for (int i = 0; i < 4; ++i) {
      int seg = i * 4 + wid;               // 0..15
      int r = seg * 8 + lrow8;
      gload_lds16(A + (size_t)(m0 + r) * K + k0 + ((lchk ^ (r & 7)) << 3),
                  As + buf * 8192 + seg * 512);
    }
#pragma unroll
    for (int i = 0; i < 2; ++i) {
      int seg = i * 4 + wid;               // 0..7
      int r = seg * 8 + lrow8;
      gload_lds16(Bt + (size_t)(n0 + r) * K + k0 + ((lchk ^ (r & 7)) << 3),
                  Bs + buf * 4096 + seg * 512);
    }
  };

  stage(0, 0);
  __syncthreads();
  const int nk = K >> 6;   // 14
  int cur = 0;
  for (int t = 0; t < nk; ++t) {
    if (t + 1 < nk) stage(cur ^ 1, (t + 1) << 6);
#pragma unroll
    for (int kk = 0; kk < 2; ++kk) {
      bf16x8 am[4], bn[2];
#pragma unroll
      for (int mf = 0; mf < 4; ++mf) {
        int row = wr * 64 + mf * 16 + lr;
        am[mf] = *reinterpret_cast<const bf16x8*>(
            (char*)(As + cur * 8192 + row * 64) + ((kk * 64 + lh * 16) ^ ((row & 7) << 4)));
      }
#pragma unroll
      for (int nf = 0; nf < 2; ++nf) {
        int row = wc * 32 + nf * 16 + lr;
        bn[nf] = *reinterpret_cast<const bf16x8*>(
            (char*)(Bs + cur * 4096 + row * 64) + ((kk * 64 + lh * 16) ^ ((row & 7) << 4)));
      }
      __builtin_amdgcn_s_setprio(1);
#pragma unroll
      for (int mf = 0; mf < 4; ++mf)
#pragma unroll
        for (int nf = 0; nf < 2; ++nf)
          acc[mf][nf] = mfma16(am[mf], bn[nf], acc[mf][nf]);
      __builtin_amdgcn_s_setprio(0);
    }
    __syncthreads();   // also makes As/Bs dead after the last iteration
    cur ^= 1;
  }

  // ---- store acc (+bias) to LDS f32 tile ----
#pragma unroll
  for (int nf = 0; nf < 2; ++nf) {
    int col = wc * 32 + nf * 16 + lr;
    float bb = bias[n0 + col];
#pragma unroll
    for (int mf = 0; mf < 4; ++mf) {
      int row0 = wr * 64 + mf * 16 + lh * 4;
#pragma unroll
      for (int j = 0; j < 4; ++j)
        tileO[(row0 + j) * 65 + col] = acc[mf][nf][j] + bb;
    }
  }
  __syncthreads();

  const float QSCALE = 0.125f * 1.44269504088896f;  // 1/sqrt(64) * log2(e)
  int b = blockIdx.y >> 4;
  int s0 = (blockIdx.y & 15) * 128;
  int bx = blockIdx.x;
  if (bx < 14) {
    // Q head: rope + scale, plain [b][h][s][64]
    int r2 = tid >> 1, half = tid & 1;
    int s = s0 + r2;
    const float* tr = trig + (size_t)s * 64;
    size_t base = ((size_t)(b * NHEADS + bx) * S_LEN + s) * HDIM;
    bf16x8 o1[2], o2[2];
#pragma unroll
    for (int v = 0; v < 2; ++v)
#pragma unroll
      for (int p = 0; p < 8; ++p) {
        int d = half * 16 + v * 8 + p;
        float c = tr[d], sn = tr[32 + d];
        float v1 = tileO[r2 * 65 + d], v2 = tileO[r2 * 65 + d + 32];
        o1[v][p] = (bf16)((v1 * c - v2 * sn) * QSCALE);
        o2[v][p] = (bf16)((v2 * c + v1 * sn) * QSCALE);
      }
    *(bf16x8*)(Qb + base + half * 16)      = o1[0];
    *(bf16x8*)(Qb + base + half * 16 + 8)  = o1[1];
    *(bf16x8*)(Qb + base + 32 + half * 16)     = o2[0];
    *(bf16x8*)(Qb + base + 32 + half * 16 + 8) = o2[1];
  } else if (bx < 16) {
    // K head: rope + XOR swizzle d ^ (((s&7)^((s>>3)&1))<<3)
    int kh = bx - 14;
    int r2 = tid >> 1, half = tid & 1;
    int s = s0 + r2;
    const float* tr = trig + (size_t)s * 64;
    int sw = (((s & 7) ^ ((s >> 3) & 1)) << 3);
    size_t base = ((size_t)(b * NKVH + kh) * S_LEN + s) * HDIM;
#pragma unroll
    for (int p = 0; p < 16; ++p) {
      int d = half * 16 + p;
      float c = tr[d], sn = tr[32 + d];
      float v1 = tileO[r2 * 65 + d], v2 = tileO[r2 * 65 + d + 32];
      Kb[base + (d ^ sw)]        = (bf16)(v1 * c - v2 * sn);
      Kb[base + ((d + 32) ^ sw)] = (bf16)(v2 * c + v1 * sn);
    }
  } else {
    // V head: transpose to [b][kv][64][S], col (s&63) ^ ((d&7)<<3)
    int kh = bx - 16;
    int d = tid & 63, seg = tid >> 6;
    size_t vbase = ((size_t)(b * NKVH + kh) * HDIM + d) * S_LEN;
    int c8 = (d & 7) << 3;
#pragma unroll
    for (int g = 0; g < 4; ++g) {
      int sl = seg * 32 + g * 8;   // aligned-8 s_local run
      bf16x8 w;
#pragma unroll
      for (int p = 0; p < 8; ++p)
        w[p] = (bf16)tileO[(sl + p) * 65 + d];
      int s = s0 + sl;
      int col = (s & ~63) | (((s & 63) ^ c8) & ~7);
      *(bf16x8*)(Vt + vbase + col) = w;
    }
  }
}

// ---------------- GEMM: C[M][N] = A[M][K](bf16) * Bt[N][K](bf16)^T (f32 out, BK=64) ----------------
__global__ __launch_bounds__(256) void gemm_bt_kernel(const bf16* __restrict__ A,
                                                      const bf16* __restrict__ Bt,
                                                      float* __restrict__ C,
                                                      int M, int N, int K) {
  __shared__ __align__(16) bf16 As[2][128][64];
  __shared__ __align__(16) bf16 Bs[2][64][64];
  int n0 = blockIdx.x * 64, m0 = blockIdx.y * 128;
  int tid = threadIdx.x;
  int wid = tid >> 6, lane = tid & 63;
  int lr = lane & 15, lh = lane >> 4;
  int wr = wid >> 1, wc = wid & 1;
  int lrow8 = lane >> 3, lchk = lane & 7;
  f32x4 acc[4][2] = {};

  auto stage = [&](int buf, int k0) {
#pragma unroll
    for (int i = 0; i < 4; ++i) {
      int seg = i * 4 + wid;
      int r = seg * 8 + lrow8;
      gload_lds16(A + (size_t)(m0 + r) * K + k0 + ((lchk ^ (r & 7)) << 3),
                  &As[buf][0][0] + seg * 512);
    }
#pragma unroll
    for (int i = 0; i < 2; ++i) {
      int seg = i * 4 + wid;
      int r = seg * 8 + lrow8;
      gload_lds16(Bt + (size_t)(n0 + r) * K + k0 + ((lchk ^ (r & 7)) << 3),
                  &Bs[buf][0][0] + seg * 512);
    }
  };

  stage(0, 0);
  __syncthreads();
  int nk = K >> 6;
  int cur = 0;
  for (int t = 0; t < nk; ++t) {
    if (t + 1 < nk) stage(cur ^ 1, (t + 1) << 6);
#pragma unroll
    for (int kk = 0; kk < 2; ++kk) {
      bf16x8 am[4], bn[2];
#pragma unroll
      for (int mf = 0; mf < 4; ++mf) {
        int row = wr * 64 + mf * 16 + lr;
        am[mf] = *reinterpret_cast<const bf16x8*>(
            (char*)&As[cur][row][0] + ((kk * 64 + lh * 16) ^ ((row & 7) << 4)));
      }
#pragma unroll
      for (int nf = 0; nf < 2; ++nf) {
        int row = wc * 32 + nf * 16 + lr;
        bn[nf] = *reinterpret_cast<const bf16x8*>(
            (char*)&Bs[cur][row][0] + ((kk * 64 + lh * 16) ^ ((row & 7) << 4)));
      }
      __builtin_amdgcn_s_setprio(1);
#pragma unroll
      for (int mf = 0; mf < 4; ++mf)
#pragma unroll
        for (int nf = 0; nf < 2; ++nf)
          acc[mf][nf] = mfma16(am[mf], bn[nf], acc[mf][nf]);
      __builtin_amdgcn_s_setprio(0);
    }
    __syncthreads();
    cur ^= 1;
  }

#pragma unroll
  for (int nf = 0; nf < 2; ++nf) {
    int col = n0 + wc * 32 + nf * 16 + lr;
#pragma unroll
    for (int mf = 0; mf < 4; ++mf) {
      int row0 = m0 + wr * 64 + mf * 16 + lh * 4;
#pragma unroll
      for (int j = 0; j < 4; ++j)
        C[(size_t)(row0 + j) * N + col] = acc[mf][nf][j];
    }
  }
}

// ---------------- flash attention: shuffle-free steady-state softmax + T5 setprio ----------------
// Opart: [28][40][128][64] bf16, Oml: [28][40][128][2] f32 (m, l in log2 domain)
__global__ __launch_bounds__(256, 4) void attn_kernel(const bf16* __restrict__ Qb,
                                                      const bf16* __restrict__ Kb,
                                                      const bf16* __restrict__ Vt,
                                                      bf16* __restrict__ Opart,
                                                      float* __restrict__ Oml,
                                                      bf16* __restrict__ Ob) {
  int blk = blockIdx.x;
  int c = chunk_order[blk % NCHUNK], bh = blk / NCHUNK;
  int qt, ch;
  chunk_map(c, qt, ch);
  int h = bh % NHEADS, b = bh / NHEADS;
  int q0 = qt * 128;
  int kv = h / 7;
  int kc0 = ch * 512;
  int kend = min(kc0 + 512, q0 + 128);
  int nt = (kend - kc0) >> 6;
  int tid = threadIdx.x, wid = tid >> 6, lane = tid & 63;
  int lr = lane & 15, lh = lane >> 4;
  int swk = (lr & 7) << 4;   // byte XOR for V LDS reads

  const bf16* Qp = Qb + ((size_t)(b * NHEADS + h) * S_LEN + q0 + wid * 32) * HDIM;
  const char* KpB = (const char*)(Kb + (size_t)(b * NKVH + kv) * S_LEN * HDIM);
  const char* VpB = (const char*)(Vt + (size_t)(b * NKVH + kv) * HDIM * S_LEN);

  __shared__ __align__(16) bf16 Ks[2][4096];
  __shared__ __align__(16) bf16 Vs[2][4096];

  bf16x8 aq[2][2];
#pragma unroll
  for (int f = 0; f < 2; ++f)
#pragma unroll
    for (int kk = 0; kk < 2; ++kk)
      aq[f][kk] = *reinterpret_cast<const bf16x8*>(
          Qp + (size_t)(f * 16 + lr) * HDIM + kk * 32 + lh * 8);

  float m[2] = {-3.0e38f, -3.0e38f}, l[2] = {0.f, 0.f};
  f32x4 o[2][4] = {};

  auto stage = [&](int buf, int kv0) {
#pragma unroll
    for (int i = 0; i < 2; ++i) {
      gload_lds16b(KpB + (size_t)kv0 * 128 + wid * 2048 + i * 1024 + lane * 16,
                   &Ks[buf][wid * 1024 + i * 512]);
      int d = wid * 16 + i * 8 + (lane >> 3);
      gload_lds16b(VpB + (size_t)d * (S_LEN * 2) + kv0 * 2 + (lane & 7) * 16,
                   &Vs[buf][wid * 1024 + i * 512]);
    }
  };

  stage(0, kc0);
  __syncthreads();

  int qf0 = q0 + wid * 32;
  int cur = 0;
  for (int t = 0; t < nt; ++t) {
    int kv0 = kc0 + (t << 6);
    // ---- swapped QK^T: sacc[f][nf][j] = S[q = qf0+f*16+lr][k = kv0+g(nf, lh*4+j)] ----
    const char* KsB = (const char*)&Ks[cur][0];
    f32x4 sacc[2][4] = {};
#pragma unroll
    for (int nf = 0; nf < 4; ++nf) {
      int rowk = 8 * (lr >> 2) + (lr & 3) + ((nf & 1) << 2) + ((nf >> 1) << 5);
      int rsw = (((rowk & 7) ^ ((rowk >> 3) & 1)) << 4);
#pragma unroll
      for (int kk = 0; kk < 2; ++kk) {
        bf16x8 kb = *(const bf16x8*)(KsB + rowk * 128 + ((kk * 64 + lh * 16) ^ rsw));
        __builtin_amdgcn_s_setprio(1);
        sacc[0][nf] = mfma16(kb, aq[0][kk], sacc[0][nf]);
        sacc[1][nf] = mfma16(kb, aq[1][kk], sacc[1][nf]);
        __builtin_amdgcn_s_setprio(0);
      }
    }
    if (t + 1 < nt) stage(cur ^ 1, kv0 + 64);

    // ---- mask (wave-uniform skip) + LANE-LOCAL max (no shuffles) ----
    float lmax[2];
#pragma unroll
    for (int f = 0; f < 2; ++f) {
      int qg = qf0 + f * 16 + lr;
      if (kv0 + 63 > qf0 + f * 16) {
#pragma unroll
        for (int nf = 0; nf < 4; ++nf) {
          int kb0 = kv0 + ((nf & 1) << 2) + ((nf >> 1) << 5) + (lh << 3);
#pragma unroll
          for (int j = 0; j < 4; ++j)
            if (kb0 + j > qg) sacc[f][nf][j] = -3.0e38f;
        }
      }
      f32x4 m01, m23;
#pragma unroll
      for (int j = 0; j < 4; ++j) {
        m01[j] = fmaxf(sacc[f][0][j], sacc[f][1][j]);
        m23[j] = fmaxf(sacc[f][2][j], sacc[f][3][j]);
      }
      f32x4 m4;
#pragma unroll
      for (int j = 0; j < 4; ++j) m4[j] = fmaxf(m01[j], m23[j]);
      lmax[f] = fmaxf(fmaxf(m4[0], m4[1]), fmaxf(m4[2], m4[3]));
    }
    // ---- defer-max guard: cross-lane reduce + rescale only on growth > 8 ----
    float g = fmaxf(lmax[0] - m[0], lmax[1] - m[1]);
    if (!__all(g <= 8.0f)) {
#pragma unroll
      for (int f = 0; f < 2; ++f) {
        float mxl = fmaxf(lmax[f], __shfl_xor(lmax[f], 16));
        mxl = fmaxf(mxl, __shfl_xor(mxl, 32));
        float mn = fmaxf(m[f], mxl);
        float al = exp2f(m[f] - mn);
        m[f] = mn;
        l[f] *= al;
        f32x4 av;
#pragma unroll
        for (int j = 0; j < 4; ++j) av[j] = __shfl(al, (lh << 2) + j);
#pragma unroll
        for (int nf = 0; nf < 4; ++nf) o[f][nf] *= av;
      }
    }
    // ---- exp2 + LANE-PARTIAL sum (no shuffles) + in-register P pack ----
    bf16x8 pa[2][2];
#pragma unroll
    for (int f = 0; f < 2; ++f) {
      f32x4 rs4 = {0.f, 0.f, 0.f, 0.f};
#pragma unroll
      for (int nf = 0; nf < 4; ++nf) {
#pragma unroll
        for (int j = 0; j < 4; ++j)
          sacc[f][nf][j] = exp2f(sacc[f][nf][j] - m[f]);
        rs4 += sacc[f][nf];
      }
      l[f] += (rs4[0] + rs4[1]) + (rs4[2] + rs4[3]);   // lane-partial
#pragma unroll
      for (int kk = 0; kk < 2; ++kk) {
        u32x4 w;
        w[0] = cvtpk(sacc[f][2 * kk][0], sacc[f][2 * kk][1]);
        w[1] = cvtpk(sacc[f][2 * kk][2], sacc[f][2 * kk][3]);
        w[2] = cvtpk(sacc[f][2 * kk + 1][0], sacc[f][2 * kk + 1][1]);
        w[3] = cvtpk(sacc[f][2 * kk + 1][2], sacc[f][2 * kk + 1][3]);
        pa[f][kk] = __builtin_bit_cast(bf16x8, w);
      }
    }
    // ---- PV ----
    const char* VsB = (const char*)&Vs[cur][0];
#pragma unroll
    for (int nf = 0; nf < 4; ++nf) {
#pragma unroll
      for (int kk = 0; kk < 2; ++kk) {
        bf16x8 vb = *(const bf16x8*)(VsB + (nf * 16 + lr) * 128 + ((kk * 64 + lh * 16) ^ swk));
        __builtin_amdgcn_s_setprio(1);
        o[0][nf] = mfma16(pa[0][kk], vb, o[0][nf]);
        o[1][nf] = mfma16(pa[1][kk], vb, o[1][nf]);
        __builtin_amdgcn_s_setprio(0);
      }
    }
    __syncthreads();   // drains staging vmcnt + protects buffer flip
    cur ^= 1;
  }

  // complete the row-sums: combine the 4 lane-partials of each row (once per chunk)
#pragma unroll
  for (int f = 0; f < 2; ++f) {
    l[f] += __shfl_xor(l[f], 16);
    l[f] += __shfl_xor(l[f], 32);
  }

  if (qt < 4) {
    // single-chunk q-tile: write normalized output directly to Ob (skip combine).
    // l[f] is lane-local to q-row lr; o[f][nf][j] lives at row lh*4+j -> transpose.
#pragma unroll
    for (int f = 0; f < 2; ++f) {
      f32x4 inv4;
#pragma unroll
      for (int j = 0; j < 4; ++j)
        inv4[j] = 1.0f / __shfl(l[f], (lh << 2) + j);
#pragma unroll
      for (int nf = 0; nf < 4; ++nf) {
        int col = h * 64 + nf * 16 + lr;
#pragma unroll
        for (int j = 0; j < 4; ++j) {
          int rloc = wid * 32 + f * 16 + (lh << 2) + j;
          Ob[((size_t)(b * S_LEN) + q0 + rloc) * HID + col] = (bf16)(o[f][nf][j] * inv4[j]);
        }
      }
    }
    return;
  }

  // epilogue: write unnormalized partial O (bf16) + per-row (m, l)
  size_t pbase = ((size_t)bh * NCHUNK + c) * (128 * 64);
#pragma unroll
  for (int f = 0; f < 2; ++f)
#pragma unroll
    for (int nf = 0; nf < 4; ++nf) {
      int col = nf * 16 + lr;
#pragma unroll
      for (int j = 0; j < 4; ++j) {
        int rloc = wid * 32 + f * 16 + (lh << 2) + j;
        Opart[pbase + (size_t)rloc * 64 + col] = (bf16)o[f][nf][j];
      }
    }
  if (lane < 16) {
    size_t mbase = ((size_t)bh * NCHUNK + c) * 128;
#pragma unroll
    for (int f = 0; f < 2; ++f) {
      int rloc = wid * 32 + f * 16 + lane;
      Oml[(mbase + rloc) * 2]     = m[f];
      Oml[(mbase + rloc) * 2 + 1] = l[f];
    }
  }
}

// ---------------- combine partials (qt >= 4 only; m in log2 domain) ----------------
__global__ __launch_bounds__(256) void combine_kernel(const bf16* __restrict__ Opart,
                                                      const float* __restrict__ Oml,
                                                      bf16* __restrict__ Ob) {
  int blk = blockIdx.x;            // bh*12 + (qt-4)
  int qt = 4 + blk % 12, bh = blk / 12;
  int h = bh % NHEADS, b = bh / NHEADS;
  int a = qt >> 2, bb = qt & 3;
  int nch = a + 1;
  int coff = (a + 1) * (2 * a + bb);
  int t = threadIdx.x;
  int row = t >> 1, cg = t & 1;    // 32 cols per thread

  float M = -__builtin_inff();
  for (int i = 0; i < nch; ++i)
    M = fmaxf(M, Oml[(((size_t)bh * NCHUNK + coff + i) * 128 + row) * 2]);
  float L = 0.f;
  for (int i = 0; i < nch; ++i) {
    size_t mb = (((size_t)bh * NCHUNK + coff + i) * 128 + row) * 2;
    L += exp2f(Oml[mb] - M) * Oml[mb + 1];
  }
  float acc[32];
#pragma unroll
  for (int k = 0; k < 32; ++k) acc[k] = 0.f;
  for (int i = 0; i < nch; ++i) {
    size_t mb = (((size_t)bh * NCHUNK + coff + i) * 128 + row) * 2;
    float w = exp2f(Oml[mb] - M);
    const bf16* src = Opart + (((size_t)bh * NCHUNK + coff + i) * 128 + row) * 64 + cg * 32;
#pragma unroll
    for (int v = 0; v < 4; ++v) {
      bf16x8 x = *reinterpret_cast<const bf16x8*>(src + v * 8);
#pragma unroll
      for (int k = 0; k < 8; ++k) acc[v * 8 + k] += w * (float)x[k];
    }
  }
  float inv = 1.0f / L;
  bf16* dst = Ob + ((size_t)(b * S_LEN) + qt * 128 + row) * HID + h * 64 + cg * 32;
#pragma unroll
  for (int v = 0; v < 4; ++v) {
    bf16x8 r;
#pragma unroll
    for (int k = 0; k < 8; ++k) r[k] = (bf16)(acc[v * 8 + k] * inv);
    *reinterpret_cast<bf16x8*>(dst + v * 8) = r;
  }
}

// ---------------- launch ----------------
extern "C" void kernel_launch(void* const* d_in, const int* in_sizes, int n_in,
                              void* d_out, int out_size, void* d_ws, size_t ws_size,
                              hipStream_t stream) {
  (void)in_sizes; (void)n_in; (void)out_size; (void)ws_size;
  const float* X  = (const float*)d_in[0];
  const float* Wq = (const float*)d_in[2];
  const float* bq = (const float*)d_in[3];
  const float* Wk = (const float*)d_in[4];
  const float* bk = (const float*)d_in[5];
  const float* Wv = (const float*)d_in[6];
  const float* bv = (const float*)d_in[7];
  const float* Wo = (const float*)d_in[8];
  float* OUT = (float*)d_out;

  char* ws = (char*)d_ws;
  bf16*  Xb    = (bf16*)(ws);                 // 4096*896*2  = 7,340,032
  bf16*  WqkvT = (bf16*)(ws + 7340032);       // 1152*896*2  = 2,064,384
  bf16*  WoT   = (bf16*)(ws + 9404416);       // 896*896*2   = 1,605,632
  float* biasq = (float*)(ws + 11010048);     // 1152*4
  bf16*  Opart = (bf16*)(ws + 11014656);      // 28*40*128*64*2 = 18,350,080
  float* trig  = (float*)(ws + 29364736);     // 2048*64*4 = 524,288 (ends 29,889,024)
  bf16*  Qbuf  = (bf16*)(ws + 29889024);      // 4096*896*2
  bf16*  Kbuf  = (bf16*)(ws + 37229056);      // 2*2*2048*64*2
  bf16*  Vbuf  = (bf16*)(ws + 38277632);      // 2*2*64*2048*2  (ends 39,326,208)
  float* Oml   = (float*)(ws + 7340032);      // reuse WqkvT region after GEMM1 (1,146,880)
  bf16*  Obuf  = Xb;                          // reuse (Xb dead after GEMM1)

  prep_kernel<<<5637, 256, 0, stream>>>(X, Xb, Wq, Wk, Wv, Wo, WqkvT, WoT,
                                        bq, bk, bv, biasq, trig);
  gemm_qkv_kernel<<<dim3(18, 32), 256, 0, stream>>>(Xb, WqkvT, biasq, trig,
                                                    Qbuf, Kbuf, Vbuf);
  attn_kernel<<<28 * NCHUNK, 256, 0, stream>>>(Qbuf, Kbuf, Vbuf, Opart, Oml, Obuf);
  combine_kernel<<<28 * 12, 256, 0, stream>>>(Opart, Oml, Obuf);
  gemm_bt_kernel<<<dim3(14, 32), 256, 0, stream>>>(Obuf, WoT, OUT, 4096, 896, 896);
}

// Round 17
// 95.664 us; speedup vs baseline: 1.0598x; 1.0140x over previous
//
#include <hip/hip_runtime.h>

#define S_LEN 2048
#define NHEADS 14
#define NKVH 2
#define HDIM 64
#define HID 896
#define NQKV 1152
#define NCHUNK 40   // per bh: sum over 16 q-blocks(128 rows) of ceil(128*(qt+1)/512)

typedef __bf16 bf16;
typedef __bf16 bf16x4 __attribute__((ext_vector_type(4)));
typedef __bf16 bf16x8 __attribute__((ext_vector_type(8)));
typedef float f32x4 __attribute__((ext_vector_type(4)));
typedef unsigned int u32x4 __attribute__((ext_vector_type(4)));

__device__ inline f32x4 mfma16(bf16x8 a, bf16x8 b, f32x4 c) {
  return __builtin_amdgcn_mfma_f32_16x16x32_bf16(a, b, c, 0, 0, 0);
}

__device__ inline void gload_lds16(const bf16* g, bf16* l) {
  __builtin_amdgcn_global_load_lds(
      (const __attribute__((address_space(1))) void*)g,
      (__attribute__((address_space(3))) void*)l, 16, 0, 0);
}
__device__ inline void gload_lds16b(const void* g, void* l) {
  __builtin_amdgcn_global_load_lds(
      (const __attribute__((address_space(1))) void*)g,
      (__attribute__((address_space(3))) void*)l, 16, 0, 0);
}

__device__ inline unsigned cvtpk(float lo, float hi) {
  unsigned r;
  asm("v_cvt_pk_bf16_f32 %0, %1, %2" : "=v"(r) : "v"(lo), "v"(hi));
  return r;
}

// chunk index c (0..39) -> (q-block qt 0..15, chunk-within ch); nch(qt)=(qt>>2)+1
__device__ inline void chunk_map(int c, int& qt, int& ch) {
  if (c < 4)       { qt = c;                ch = 0; }
  else if (c < 12) { qt = 4 + ((c - 4) >> 1); ch = (c - 4) & 1; }
  else if (c < 24) { int d = c - 12; qt = 8 + d / 3; ch = d % 3; }
  else             { int d = c - 24; qt = 12 + (d >> 2); ch = d & 3; }
}

// chunks sorted by tile-length descending (28 eights, 4 sixes, 4 fours, 4 twos):
// per-CU length-sums equalize (snake-LPT) while keeping bh-major locality.
__device__ const int chunk_order[NCHUNK] = {
  36, 37, 38, 39, 32, 33, 34, 28, 29, 30, 24, 25, 26, 21, 22, 23,
  18, 19, 15, 16, 12, 13, 10, 11, 8, 6, 4, 3,
  35, 20, 9, 2,   // sixes
  31, 17, 7, 1,   // fours
  27, 14, 5, 0    // twos
};

// ---------------- fused prep: cast X, transpose-cast all W, pack bias, trig table ----------------
__global__ __launch_bounds__(256) void prep_kernel(
    const float* __restrict__ X, bf16* __restrict__ Xb,
    const float* __restrict__ Wq, const float* __restrict__ Wk,
    const float* __restrict__ Wv, const float* __restrict__ Wo,
    bf16* __restrict__ WqkvT, bf16* __restrict__ WoT,
    const float* __restrict__ bq, const float* __restrict__ bk,
    const float* __restrict__ bv, float* __restrict__ biasq,
    float* __restrict__ trig) {
  __shared__ float tile[32][33];
  int blk = blockIdx.x;
  int tid = threadIdx.x;
  if (blk < 3584) {
    int i = blk * 256 + tid;
    if (i < 917504) {
      float4 v = reinterpret_cast<const float4*>(X)[i];
      bf16x4 o;
      o[0] = (bf16)v.x; o[1] = (bf16)v.y; o[2] = (bf16)v.z; o[3] = (bf16)v.w;
      reinterpret_cast<bf16x4*>(Xb)[i] = o;
    }
    return;
  }
  if (blk < 5376) {
    int t = blk - 3584;
    const float* W; bf16* dst; int N, bx, by;
    if (t < 784)       { W = Wq; dst = WqkvT;                      N = 896; bx = t % 28;          by = t / 28; }
    else if (t < 896)  { int u = t - 784;  W = Wk; dst = WqkvT + (size_t)896 * 896;  N = 128; bx = u % 4; by = u / 4; }
    else if (t < 1008) { int u = t - 896;  W = Wv; dst = WqkvT + (size_t)1024 * 896; N = 128; bx = u % 4; by = u / 4; }
    else               { int u = t - 1008; W = Wo; dst = WoT;      N = 896; bx = u % 28;          by = u / 28; }
    int n0 = bx * 32, k0 = by * 32;
    int tx = tid & 31, ty = tid >> 5;  // 32 x 8
#pragma unroll
    for (int j = 0; j < 32; j += 8)
      tile[ty + j][tx] = W[(size_t)(k0 + ty + j) * N + n0 + tx];
    __syncthreads();
#pragma unroll
    for (int j = 0; j < 32; j += 8)
      dst[(size_t)(n0 + ty + j) * HID + k0 + tx] = (bf16)tile[tx][ty + j];
    return;
  }
  if (blk < 5381) {
    int i = (blk - 5376) * 256 + tid;
    if (i < 896) biasq[i] = bq[i];
    else if (i < 1024) biasq[i] = bk[i - 896];
    else if (i < 1152) biasq[i] = bv[i - 1024];
    return;
  }
  // trig table: [2048][64] = cos at [s][d], sin at [s][32+d], d=0..31
  {
    int ti = blk - 5381;                 // 0..255
    int s = ti * 8 + (tid >> 5);
    int d = tid & 31;
    float inv = expf(-(float)d * (13.815510557964274f / 32.0f));  // 1e6^(-d/32)
    float a = (float)s * inv;
    float c, si;
    sincosf(a, &si, &c);
    trig[(size_t)s * 64 + d] = c;
    trig[(size_t)s * 64 + 32 + d] = si;
  }
}

// ---------------- GEMM1 fused with RoPE + Q/K/V layout (BK=64, swizzled LDS) ----------------
// LDS: linear dest; source 16B-chunk pre-permuted chunk^=(row&7); reads XOR ((row&7)<<4).
__global__ __launch_bounds__(256) void gemm_qkv_kernel(const bf16* __restrict__ A,
                                                       const bf16* __restrict__ Bt,
                                                       const float* __restrict__ bias,
                                                       const float* __restrict__ trig,
                                                       bf16* __restrict__ Qb,
                                                       bf16* __restrict__ Kb,
                                                       bf16* __restrict__ Vt) {
  __shared__ __align__(16) char smem[49152];
  bf16* As = (bf16*)smem;              // [2][128][64] = 32768 B
  bf16* Bs = (bf16*)(smem + 32768);    // [2][64][64]  = 16384 B
  float* tileO = (float*)smem;         // [128][65] f32 = 33280 B (aliases, used after loop)
  const int K = 896;
  int n0 = blockIdx.x * 64, m0 = blockIdx.y * 128;
  int tid = threadIdx.x;
  int wid = tid >> 6, lane = tid & 63;
  int lr = lane & 15, lh = lane >> 4;
  int wr = wid >> 1, wc = wid & 1;
  int lrow8 = lane >> 3, lchk = lane & 7;   // staging: 8 rows x 8 chunks per segment
  f32x4 acc[4][2] = {};

  auto stage = [&](int buf, int k0) {
#pragma unroll
    for (int i = 0; i < 4; ++i) {
      int seg = i * 4 + wid;               // 0..15
      int r = seg * 8 + lrow8;
      gload_lds16(A + (size_t)(m0 + r) * K + k0 + ((lchk ^ (r & 7)) << 3),
                  As + buf * 8192 + seg * 512);
    }
#pragma unroll
    for (int i = 0; i < 2; ++i) {
      int seg = i * 4 + wid;               // 0..7
      int r = seg * 8 + lrow8;
      gload_lds16(Bt + (size_t)(n0 + r) * K + k0 + ((lchk ^ (r & 7)) << 3),
                  Bs + buf * 4096 + seg * 512);
    }
  };

  stage(0, 0);
  __syncthreads();
  const int nk = K >> 6;   // 14
  int cur = 0;
  for (int t = 0; t < nk; ++t) {
    if (t + 1 < nk) stage(cur ^ 1, (t + 1) << 6);
#pragma unroll
    for (int kk = 0; kk < 2; ++kk) {
      bf16x8 am[4], bn[2];
#pragma unroll
      for (int mf = 0; mf < 4; ++mf) {
        int row = wr * 64 + mf * 16 + lr;
        am[mf] = *reinterpret_cast<const bf16x8*>(
            (char*)(As + cur * 8192 + row * 64) + ((kk * 64 + lh * 16) ^ ((row & 7) << 4)));
      }
#pragma unroll
      for (int nf = 0; nf < 2; ++nf) {
        int row = wc * 32 + nf * 16 + lr;
        bn[nf] = *reinterpret_cast<const bf16x8*>(
            (char*)(Bs + cur * 4096 + row * 64) + ((kk * 64 + lh * 16) ^ ((row & 7) << 4)));
      }
      __builtin_amdgcn_s_setprio(1);
#pragma unroll
      for (int mf = 0; mf < 4; ++mf)
#pragma unroll
        for (int nf = 0; nf < 2; ++nf)
          acc[mf][nf] = mfma16(am[mf], bn[nf], acc[mf][nf]);
      __builtin_amdgcn_s_setprio(0);
    }
    __syncthreads();   // also makes As/Bs dead after the last iteration
    cur ^= 1;
  }

  // ---- store acc (+bias) to LDS f32 tile ----
#pragma unroll
  for (int nf = 0; nf < 2; ++nf) {
    int col = wc * 32 + nf * 16 + lr;
    float bb = bias[n0 + col];
#pragma unroll
    for (int mf = 0; mf < 4; ++mf) {
      int row0 = wr * 64 + mf * 16 + lh * 4;
#pragma unroll
      for (int j = 0; j < 4; ++j)
        tileO[(row0 + j) * 65 + col] = acc[mf][nf][j] + bb;
    }
  }
  __syncthreads();

  const float QSCALE = 0.125f * 1.44269504088896f;  // 1/sqrt(64) * log2(e)
  int b = blockIdx.y >> 4;
  int s0 = (blockIdx.y & 15) * 128;
  int bx = blockIdx.x;
  if (bx < 14) {
    // Q head: rope + scale, plain [b][h][s][64]
    int r2 = tid >> 1, half = tid & 1;
    int s = s0 + r2;
    const float* tr = trig + (size_t)s * 64;
    size_t base = ((size_t)(b * NHEADS + bx) * S_LEN + s) * HDIM;
    bf16x8 o1[2], o2[2];
#pragma unroll
    for (int v = 0; v < 2; ++v)
#pragma unroll
      for (int p = 0; p < 8; ++p) {
        int d = half * 16 + v * 8 + p;
        float c = tr[d], sn = tr[32 + d];
        float v1 = tileO[r2 * 65 + d], v2 = tileO[r2 * 65 + d + 32];
        o1[v][p] = (bf16)((v1 * c - v2 * sn) * QSCALE);
        o2[v][p] = (bf16)((v2 * c + v1 * sn) * QSCALE);
      }
    *(bf16x8*)(Qb + base + half * 16)      = o1[0];
    *(bf16x8*)(Qb + base + half * 16 + 8)  = o1[1];
    *(bf16x8*)(Qb + base + 32 + half * 16)     = o2[0];
    *(bf16x8*)(Qb + base + 32 + half * 16 + 8) = o2[1];
  } else if (bx < 16) {
    // K head: rope + XOR swizzle d ^ (((s&7)^((s>>3)&1))<<3)
    int kh = bx - 14;
    int r2 = tid >> 1, half = tid & 1;
    int s = s0 + r2;
    const float* tr = trig + (size_t)s * 64;
    int sw = (((s & 7) ^ ((s >> 3) & 1)) << 3);
    size_t base = ((size_t)(b * NKVH + kh) * S_LEN + s) * HDIM;
#pragma unroll
    for (int p = 0; p < 16; ++p) {
      int d = half * 16 + p;
      float c = tr[d], sn = tr[32 + d];
      float v1 = tileO[r2 * 65 + d], v2 = tileO[r2 * 65 + d + 32];
      Kb[base + (d ^ sw)]        = (bf16)(v1 * c - v2 * sn);
      Kb[base + ((d + 32) ^ sw)] = (bf16)(v2 * c + v1 * sn);
    }
  } else {
    // V head: transpose to [b][kv][64][S], col (s&63) ^ ((d&7)<<3)
    int kh = bx - 16;
    int d = tid & 63, seg = tid >> 6;
    size_t vbase = ((size_t)(b * NKVH + kh) * HDIM + d) * S_LEN;
    int c8 = (d & 7) << 3;
#pragma unroll
    for (int g = 0; g < 4; ++g) {
      int sl = seg * 32 + g * 8;   // aligned-8 s_local run
      bf16x8 w;
#pragma unroll
      for (int p = 0; p < 8; ++p)
        w[p] = (bf16)tileO[(sl + p) * 65 + d];
      int s = s0 + sl;
      int col = (s & ~63) | (((s & 63) ^ c8) & ~7);
      *(bf16x8*)(Vt + vbase + col) = w;
    }
  }
}

// ---------------- GEMM: C[M][N] = A[M][K](bf16) * Bt[N][K](bf16)^T (f32 out, BK=64) ----------------
__global__ __launch_bounds__(256) void gemm_bt_kernel(const bf16* __restrict__ A,
                                                      const bf16* __restrict__ Bt,
                                                      float* __restrict__ C,
                                                      int M, int N, int K) {
  __shared__ __align__(16) bf16 As[2][128][64];
  __shared__ __align__(16) bf16 Bs[2][64][64];
  int n0 = blockIdx.x * 64, m0 = blockIdx.y * 128;
  int tid = threadIdx.x;
  int wid = tid >> 6, lane = tid & 63;
  int lr = lane & 15, lh = lane >> 4;
  int wr = wid >> 1, wc = wid & 1;
  int lrow8 = lane >> 3, lchk = lane & 7;
  f32x4 acc[4][2] = {};

  auto stage = [&](int buf, int k0) {
#pragma unroll
    for (int i = 0; i < 4; ++i) {
      int seg = i * 4 + wid;
      int r = seg * 8 + lrow8;
      gload_lds16(A + (size_t)(m0 + r) * K + k0 + ((lchk ^ (r & 7)) << 3),
                  &As[buf][0][0] + seg * 512);
    }
#pragma unroll
    for (int i = 0; i < 2; ++i) {
      int seg = i * 4 + wid;
      int r = seg * 8 + lrow8;
      gload_lds16(Bt + (size_t)(n0 + r) * K + k0 + ((lchk ^ (r & 7)) << 3),
                  &Bs[buf][0][0] + seg * 512);
    }
  };

  stage(0, 0);
  __syncthreads();
  int nk = K >> 6;
  int cur = 0;
  for (int t = 0; t < nk; ++t) {
    if (t + 1 < nk) stage(cur ^ 1, (t + 1) << 6);
#pragma unroll
    for (int kk = 0; kk < 2; ++kk) {
      bf16x8 am[4], bn[2];
#pragma unroll
      for (int mf = 0; mf < 4; ++mf) {
        int row = wr * 64 + mf * 16 + lr;
        am[mf] = *reinterpret_cast<const bf16x8*>(
            (char*)&As[cur][row][0] + ((kk * 64 + lh * 16) ^ ((row & 7) << 4)));
      }
#pragma unroll
      for (int nf = 0; nf < 2; ++nf) {
        int row = wc * 32 + nf * 16 + lr;
        bn[nf] = *reinterpret_cast<const bf16x8*>(
            (char*)&Bs[cur][row][0] + ((kk * 64 + lh * 16) ^ ((row & 7) << 4)));
      }
      __builtin_amdgcn_s_setprio(1);
#pragma unroll
      for (int mf = 0; mf < 4; ++mf)
#pragma unroll
        for (int nf = 0; nf < 2; ++nf)
          acc[mf][nf] = mfma16(am[mf], bn[nf], acc[mf][nf]);
      __builtin_amdgcn_s_setprio(0);
    }
    __syncthreads();
    cur ^= 1;
  }

#pragma unroll
  for (int nf = 0; nf < 2; ++nf) {
    int col = n0 + wc * 32 + nf * 16 + lr;
#pragma unroll
    for (int mf = 0; mf < 4; ++mf) {
      int row0 = m0 + wr * 64 + mf * 16 + lh * 4;
#pragma unroll
      for (int j = 0; j < 4; ++j)
        C[(size_t)(row0 + j) * N + col] = acc[mf][nf][j];
    }
  }
}

// ---------------- flash attention: shuffle-free steady-state softmax (no setprio) ----------------
// Opart: [28][40][128][64] bf16, Oml: [28][40][128][2] f32 (m, l in log2 domain)
__global__ __launch_bounds__(256, 4) void attn_kernel(const bf16* __restrict__ Qb,
                                                      const bf16* __restrict__ Kb,
                                                      const bf16* __restrict__ Vt,
                                                      bf16* __restrict__ Opart,
                                                      float* __restrict__ Oml,
                                                      bf16* __restrict__ Ob) {
  int blk = blockIdx.x;
  int c = chunk_order[blk % NCHUNK], bh = blk / NCHUNK;
  int qt, ch;
  chunk_map(c, qt, ch);
  int h = bh % NHEADS, b = bh / NHEADS;
  int q0 = qt * 128;
  int kv = h / 7;
  int kc0 = ch * 512;
  int kend = min(kc0 + 512, q0 + 128);
  int nt = (kend - kc0) >> 6;
  int tid = threadIdx.x, wid = tid >> 6, lane = tid & 63;
  int lr = lane & 15, lh = lane >> 4;
  int swk = (lr & 7) << 4;   // byte XOR for V LDS reads

  const bf16* Qp = Qb + ((size_t)(b * NHEADS + h) * S_LEN + q0 + wid * 32) * HDIM;
  const char* KpB = (const char*)(Kb + (size_t)(b * NKVH + kv) * S_LEN * HDIM);
  const char* VpB = (const char*)(Vt + (size_t)(b * NKVH + kv) * HDIM * S_LEN);

  __shared__ __align__(16) bf16 Ks[2][4096];
  __shared__ __align__(16) bf16 Vs[2][4096];

  bf16x8 aq[2][2];
#pragma unroll
  for (int f = 0; f < 2; ++f)
#pragma unroll
    for (int kk = 0; kk < 2; ++kk)
      aq[f][kk] = *reinterpret_cast<const bf16x8*>(
          Qp + (size_t)(f * 16 + lr) * HDIM + kk * 32 + lh * 8);

  float m[2] = {-3.0e38f, -3.0e38f}, l[2] = {0.f, 0.f};
  f32x4 o[2][4] = {};

  auto stage = [&](int buf, int kv0) {
#pragma unroll
    for (int i = 0; i < 2; ++i) {
      gload_lds16b(KpB + (size_t)kv0 * 128 + wid * 2048 + i * 1024 + lane * 16,
                   &Ks[buf][wid * 1024 + i * 512]);
      int d = wid * 16 + i * 8 + (lane >> 3);
      gload_lds16b(VpB + (size_t)d * (S_LEN * 2) + kv0 * 2 + (lane & 7) * 16,
                   &Vs[buf][wid * 1024 + i * 512]);
    }
  };

  stage(0, kc0);
  __syncthreads();

  int qf0 = q0 + wid * 32;
  int cur = 0;
  for (int t = 0; t < nt; ++t) {
    int kv0 = kc0 + (t << 6);
    // ---- swapped QK^T: sacc[f][nf][j] = S[q = qf0+f*16+lr][k = kv0+g(nf, lh*4+j)] ----
    const char* KsB = (const char*)&Ks[cur][0];
    f32x4 sacc[2][4] = {};
#pragma unroll
    for (int nf = 0; nf < 4; ++nf) {
      int rowk = 8 * (lr >> 2) + (lr & 3) + ((nf & 1) << 2) + ((nf >> 1) << 5);
      int rsw = (((rowk & 7) ^ ((rowk >> 3) & 1)) << 4);
#pragma unroll
      for (int kk = 0; kk < 2; ++kk) {
        bf16x8 kb = *(const bf16x8*)(KsB + rowk * 128 + ((kk * 64 + lh * 16) ^ rsw));
        sacc[0][nf] = mfma16(kb, aq[0][kk], sacc[0][nf]);
        sacc[1][nf] = mfma16(kb, aq[1][kk], sacc[1][nf]);
      }
    }
    if (t + 1 < nt) stage(cur ^ 1, kv0 + 64);

    // ---- mask (wave-uniform skip) + LANE-LOCAL max (no shuffles) ----
    float lmax[2];
#pragma unroll
    for (int f = 0; f < 2; ++f) {
      int qg = qf0 + f * 16 + lr;
      if (kv0 + 63 > qf0 + f * 16) {
#pragma unroll
        for (int nf = 0; nf < 4; ++nf) {
          int kb0 = kv0 + ((nf & 1) << 2) + ((nf >> 1) << 5) + (lh << 3);
#pragma unroll
          for (int j = 0; j < 4; ++j)
            if (kb0 + j > qg) sacc[f][nf][j] = -3.0e38f;
        }
      }
      f32x4 m01, m23;
#pragma unroll
      for (int j = 0; j < 4; ++j) {
        m01[j] = fmaxf(sacc[f][0][j], sacc[f][1][j]);
        m23[j] = fmaxf(sacc[f][2][j], sacc[f][3][j]);
      }
      f32x4 m4;
#pragma unroll
      for (int j = 0; j < 4; ++j) m4[j] = fmaxf(m01[j], m23[j]);
      lmax[f] = fmaxf(fmaxf(m4[0], m4[1]), fmaxf(m4[2], m4[3]));
    }
    // ---- defer-max guard: cross-lane reduce + rescale only on growth > 8 ----
    float g = fmaxf(lmax[0] - m[0], lmax[1] - m[1]);
    if (!__all(g <= 8.0f)) {
#pragma unroll
      for (int f = 0; f < 2; ++f) {
        float mxl = fmaxf(lmax[f], __shfl_xor(lmax[f], 16));
        mxl = fmaxf(mxl, __shfl_xor(mxl, 32));
        float mn = fmaxf(m[f], mxl);
        float al = exp2f(m[f] - mn);
        m[f] = mn;
        l[f] *= al;
        f32x4 av;
#pragma unroll
        for (int j = 0; j < 4; ++j) av[j] = __shfl(al, (lh << 2) + j);
#pragma unroll
        for (int nf = 0; nf < 4; ++nf) o[f][nf] *= av;
      }
    }
    // ---- exp2 + LANE-PARTIAL sum (no shuffles) + in-register P pack ----
    bf16x8 pa[2][2];
#pragma unroll
    for (int f = 0; f < 2; ++f) {
      f32x4 rs4 = {0.f, 0.f, 0.f, 0.f};
#pragma unroll
      for (int nf = 0; nf < 4; ++nf) {
#pragma unroll
        for (int j = 0; j < 4; ++j)
          sacc[f][nf][j] = exp2f(sacc[f][nf][j] - m[f]);
        rs4 += sacc[f][nf];
      }
      l[f] += (rs4[0] + rs4[1]) + (rs4[2] + rs4[3]);   // lane-partial
#pragma unroll
      for (int kk = 0; kk < 2; ++kk) {
        u32x4 w;
        w[0] = cvtpk(sacc[f][2 * kk][0], sacc[f][2 * kk][1]);
        w[1] = cvtpk(sacc[f][2 * kk][2], sacc[f][2 * kk][3]);
        w[2] = cvtpk(sacc[f][2 * kk + 1][0], sacc[f][2 * kk + 1][1]);
        w[3] = cvtpk(sacc[f][2 * kk + 1][2], sacc[f][2 * kk + 1][3]);
        pa[f][kk] = __builtin_bit_cast(bf16x8, w);
      }
    }
    // ---- PV ----
    const char* VsB = (const char*)&Vs[cur][0];
#pragma unroll
    for (int nf = 0; nf < 4; ++nf) {
#pragma unroll
      for (int kk = 0; kk < 2; ++kk) {
        bf16x8 vb = *(const bf16x8*)(VsB + (nf * 16 + lr) * 128 + ((kk * 64 + lh * 16) ^ swk));
        o[0][nf] = mfma16(pa[0][kk], vb, o[0][nf]);
        o[1][nf] = mfma16(pa[1][kk], vb, o[1][nf]);
      }
    }
    __syncthreads();   // drains staging vmcnt + protects buffer flip
    cur ^= 1;
  }

  // complete the row-sums: combine the 4 lane-partials of each row (once per chunk)
#pragma unroll
  for (int f = 0; f < 2; ++f) {
    l[f] += __shfl_xor(l[f], 16);
    l[f] += __shfl_xor(l[f], 32);
  }

  if (qt < 4) {
    // single-chunk q-tile: write normalized output directly to Ob (skip combine).
    // l[f] is lane-local to q-row lr; o[f][nf][j] lives at row lh*4+j -> transpose.
#pragma unroll
    for (int f = 0; f < 2; ++f) {
      f32x4 inv4;
#pragma unroll
      for (int j = 0; j < 4; ++j)
        inv4[j] = 1.0f / __shfl(l[f], (lh << 2) + j);
#pragma unroll
      for (int nf = 0; nf < 4; ++nf) {
        int col = h * 64 + nf * 16 + lr;
#pragma unroll
        for (int j = 0; j < 4; ++j) {
          int rloc = wid * 32 + f * 16 + (lh << 2) + j;
          Ob[((size_t)(b * S_LEN) + q0 + rloc) * HID + col] = (bf16)(o[f][nf][j] * inv4[j]);
        }
      }
    }
    return;
  }

  // epilogue: write unnormalized partial O (bf16) + per-row (m, l)
  size_t pbase = ((size_t)bh * NCHUNK + c) * (128 * 64);
#pragma unroll
  for (int f = 0; f < 2; ++f)
#pragma unroll
    for (int nf = 0; nf < 4; ++nf) {
      int col = nf * 16 + lr;
#pragma unroll
      for (int j = 0; j < 4; ++j) {
        int rloc = wid * 32 + f * 16 + (lh << 2) + j;
        Opart[pbase + (size_t)rloc * 64 + col] = (bf16)o[f][nf][j];
      }
    }
  if (lane < 16) {
    size_t mbase = ((size_t)bh * NCHUNK + c) * 128;
#pragma unroll
    for (int f = 0; f < 2; ++f) {
      int rloc = wid * 32 + f * 16 + lane;
      Oml[(mbase + rloc) * 2]     = m[f];
      Oml[(mbase + rloc) * 2 + 1] = l[f];
    }
  }
}

// ---------------- combine partials (qt >= 4 only; m in log2 domain) ----------------
__global__ __launch_bounds__(256) void combine_kernel(const bf16* __restrict__ Opart,
                                                      const float* __restrict__ Oml,
                                                      bf16* __restrict__ Ob) {
  int blk = blockIdx.x;            // bh*12 + (qt-4)
  int qt = 4 + blk % 12, bh = blk / 12;
  int h = bh % NHEADS, b = bh / NHEADS;
  int a = qt >> 2, bb = qt & 3;
  int nch = a + 1;
  int coff = (a + 1) * (2 * a + bb);
  int t = threadIdx.x;
  int row = t >> 1, cg = t & 1;    // 32 cols per thread

  float M = -__builtin_inff();
  for (int i = 0; i < nch; ++i)
    M = fmaxf(M, Oml[(((size_t)bh * NCHUNK + coff + i) * 128 + row) * 2]);
  float L = 0.f;
  for (int i = 0; i < nch; ++i) {
    size_t mb = (((size_t)bh * NCHUNK + coff + i) * 128 + row) * 2;
    L += exp2f(Oml[mb] - M) * Oml[mb + 1];
  }
  float acc[32];
#pragma unroll
  for (int k = 0; k < 32; ++k) acc[k] = 0.f;
  for (int i = 0; i < nch; ++i) {
    size_t mb = (((size_t)bh * NCHUNK + coff + i) * 128 + row) * 2;
    float w = exp2f(Oml[mb] - M);
    const bf16* src = Opart + (((size_t)bh * NCHUNK + coff + i) * 128 + row) * 64 + cg * 32;
#pragma unroll
    for (int v = 0; v < 4; ++v) {
      bf16x8 x = *reinterpret_cast<const bf16x8*>(src + v * 8);
#pragma unroll
      for (int k = 0; k < 8; ++k) acc[v * 8 + k] += w * (float)x[k];
    }
  }
  float inv = 1.0f / L;
  bf16* dst = Ob + ((size_t)(b * S_LEN) + qt * 128 + row) * HID + h * 64 + cg * 32;
#pragma unroll
  for (int v = 0; v < 4; ++v) {
    bf16x8 r;
#pragma unroll
    for (int k = 0; k < 8; ++k) r[k] = (bf16)(acc[v * 8 + k] * inv);
    *reinterpret_cast<bf16x8*>(dst + v * 8) = r;
  }
}

// ---------------- launch ----------------
extern "C" void kernel_launch(void* const* d_in, const int* in_sizes, int n_in,
                              void* d_out, int out_size, void* d_ws, size_t ws_size,
                              hipStream_t stream) {
  (void)in_sizes; (void)n_in; (void)out_size; (void)ws_size;
  const float* X  = (const float*)d_in[0];
  const float* Wq = (const float*)d_in[2];
  const float* bq = (const float*)d_in[3];
  const float* Wk = (const float*)d_in[4];
  const float* bk = (const float*)d_in[5];
  const float* Wv = (const float*)d_in[6];
  const float* bv = (const float*)d_in[7];
  const float* Wo = (const float*)d_in[8];
  float* OUT = (float*)d_out;

  char* ws = (char*)d_ws;
  bf16*  Xb    = (bf16*)(ws);                 // 4096*896*2  = 7,340,032
  bf16*  WqkvT = (bf16*)(ws + 7340032);       // 1152*896*2  = 2,064,384
  bf16*  WoT   = (bf16*)(ws + 9404416);       // 896*896*2   = 1,605,632
  float* biasq = (float*)(ws + 11010048);     // 1152*4
  bf16*  Opart = (bf16*)(ws + 11014656);      // 28*40*128*64*2 = 18,350,080
  float* trig  = (float*)(ws + 29364736);     // 2048*64*4 = 524,288 (ends 29,889,024)
  bf16*  Qbuf  = (bf16*)(ws + 29889024);      // 4096*896*2
  bf16*  Kbuf  = (bf16*)(ws + 37229056);      // 2*2*2048*64*2
  bf16*  Vbuf  = (bf16*)(ws + 38277632);      // 2*2*64*2048*2  (ends 39,326,208)
  float* Oml   = (float*)(ws + 7340032);      // reuse WqkvT region after GEMM1 (1,146,880)
  bf16*  Obuf  = Xb;                          // reuse (Xb dead after GEMM1)

  prep_kernel<<<5637, 256, 0, stream>>>(X, Xb, Wq, Wk, Wv, Wo, WqkvT, WoT,
                                        bq, bk, bv, biasq, trig);
  gemm_qkv_kernel<<<dim3(18, 32), 256, 0, stream>>>(Xb, WqkvT, biasq, trig,
                                                    Qbuf, Kbuf, Vbuf);
  attn_kernel<<<28 * NCHUNK, 256, 0, stream>>>(Qbuf, Kbuf, Vbuf, Opart, Oml, Obuf);
  combine_kernel<<<28 * 12, 256, 0, stream>>>(Opart, Oml, Obuf);
  gemm_bt_kernel<<<dim3(14, 32), 256, 0, stream>>>(Obuf, WoT, OUT, 4096, 896, 896);
}

// Round 18
// 95.107 us; speedup vs baseline: 1.0661x; 1.0059x over previous
//
#include <hip/hip_runtime.h>

#define S_LEN 2048
#define NHEADS 14
#define NKVH 2
#define HDIM 64
#define HID 896
#define NQKV 1152
#define NCHUNK 40   // per bh: sum over 16 q-blocks(128 rows) of ceil(128*(qt+1)/512)

typedef __bf16 bf16;
typedef __bf16 bf16x4 __attribute__((ext_vector_type(4)));
typedef __bf16 bf16x8 __attribute__((ext_vector_type(8)));
typedef float f32x4 __attribute__((ext_vector_type(4)));
typedef unsigned int u32x4 __attribute__((ext_vector_type(4)));

__device__ inline f32x4 mfma16(bf16x8 a, bf16x8 b, f32x4 c) {
  return __builtin_amdgcn_mfma_f32_16x16x32_bf16(a, b, c, 0, 0, 0);
}

__device__ inline void gload_lds16(const bf16* g, bf16* l) {
  __builtin_amdgcn_global_load_lds(
      (const __attribute__((address_space(1))) void*)g,
      (__attribute__((address_space(3))) void*)l, 16, 0, 0);
}
__device__ inline void gload_lds16b(const void* g, void* l) {
  __builtin_amdgcn_global_load_lds(
      (const __attribute__((address_space(1))) void*)g,
      (__attribute__((address_space(3))) void*)l, 16, 0, 0);
}

__device__ inline unsigned cvtpk(float lo, float hi) {
  unsigned r;
  asm("v_cvt_pk_bf16_f32 %0, %1, %2" : "=v"(r) : "v"(lo), "v"(hi));
  return r;
}

// chunk index c (0..39) -> (q-block qt 0..15, chunk-within ch); nch(qt)=(qt>>2)+1
__device__ inline void chunk_map(int c, int& qt, int& ch) {
  if (c < 4)       { qt = c;                ch = 0; }
  else if (c < 12) { qt = 4 + ((c - 4) >> 1); ch = (c - 4) & 1; }
  else if (c < 24) { int d = c - 12; qt = 8 + d / 3; ch = d % 3; }
  else             { int d = c - 24; qt = 12 + (d >> 2); ch = d & 3; }
}

// chunks sorted by tile-length descending (28 eights, 4 sixes, 4 fours, 4 twos):
// per-CU length-sums equalize (snake-LPT) while keeping bh-major locality.
__device__ const int chunk_order[NCHUNK] = {
  36, 37, 38, 39, 32, 33, 34, 28, 29, 30, 24, 25, 26, 21, 22, 23,
  18, 19, 15, 16, 12, 13, 10, 11, 8, 6, 4, 3,
  35, 20, 9, 2,   // sixes
  31, 17, 7, 1,   // fours
  27, 14, 5, 0    // twos
};

// ---------------- fused prep: cast X, transpose-cast all W, pack bias, trig table ----------------
__global__ __launch_bounds__(256) void prep_kernel(
    const float* __restrict__ X, bf16* __restrict__ Xb,
    const float* __restrict__ Wq, const float* __restrict__ Wk,
    const float* __restrict__ Wv, const float* __restrict__ Wo,
    bf16* __restrict__ WqkvT, bf16* __restrict__ WoT,
    const float* __restrict__ bq, const float* __restrict__ bk,
    const float* __restrict__ bv, float* __restrict__ biasq,
    float* __restrict__ trig) {
  __shared__ float tile[32][33];
  int blk = blockIdx.x;
  int tid = threadIdx.x;
  if (blk < 3584) {
    int i = blk * 256 + tid;
    if (i < 917504) {
      float4 v = reinterpret_cast<const float4*>(X)[i];
      bf16x4 o;
      o[0] = (bf16)v.x; o[1] = (bf16)v.y; o[2] = (bf16)v.z; o[3] = (bf16)v.w;
      reinterpret_cast<bf16x4*>(Xb)[i] = o;
    }
    return;
  }
  if (blk < 5376) {
    int t = blk - 3584;
    const float* W; bf16* dst; int N, bx, by;
    if (t < 784)       { W = Wq; dst = WqkvT;                      N = 896; bx = t % 28;          by = t / 28; }
    else if (t < 896)  { int u = t - 784;  W = Wk; dst = WqkvT + (size_t)896 * 896;  N = 128; bx = u % 4; by = u / 4; }
    else if (t < 1008) { int u = t - 896;  W = Wv; dst = WqkvT + (size_t)1024 * 896; N = 128; bx = u % 4; by = u / 4; }
    else               { int u = t - 1008; W = Wo; dst = WoT;      N = 896; bx = u % 28;          by = u / 28; }
    int n0 = bx * 32, k0 = by * 32;
    int tx = tid & 31, ty = tid >> 5;  // 32 x 8
#pragma unroll
    for (int j = 0; j < 32; j += 8)
      tile[ty + j][tx] = W[(size_t)(k0 + ty + j) * N + n0 + tx];
    __syncthreads();
#pragma unroll
    for (int j = 0; j < 32; j += 8)
      dst[(size_t)(n0 + ty + j) * HID + k0 + tx] = (bf16)tile[tx][ty + j];
    return;
  }
  if (blk < 5381) {
    int i = (blk - 5376) * 256 + tid;
    if (i < 896) biasq[i] = bq[i];
    else if (i < 1024) biasq[i] = bk[i - 896];
    else if (i < 1152) biasq[i] = bv[i - 1024];
    return;
  }
  // trig table: [2048][64] = cos at [s][d], sin at [s][32+d], d=0..31
  {
    int ti = blk - 5381;                 // 0..255
    int s = ti * 8 + (tid >> 5);
    int d = tid & 31;
    float inv = expf(-(float)d * (13.815510557964274f / 32.0f));  // 1e6^(-d/32)
    float a = (float)s * inv;
    float c, si;
    sincosf(a, &si, &c);
    trig[(size_t)s * 64 + d] = c;
    trig[(size_t)s * 64 + 32 + d] = si;
  }
}

// ---------------- GEMM1 fused with RoPE + Q/K/V layout (BK=64, swizzled LDS, XCD-chunked) ----------------
// Grid is 1D (576); logical block = (orig%8)*72 + orig/8 so each XCD owns contiguous
// logical runs (full A panels stay in one XCD's L2). bx = logical%18, by = logical/18.
__global__ __launch_bounds__(256) void gemm_qkv_kernel(const bf16* __restrict__ A,
                                                       const bf16* __restrict__ Bt,
                                                       const float* __restrict__ bias,
                                                       const float* __restrict__ trig,
                                                       bf16* __restrict__ Qb,
                                                       bf16* __restrict__ Kb,
                                                       bf16* __restrict__ Vt) {
  __shared__ __align__(16) char smem[49152];
  bf16* As = (bf16*)smem;              // [2][128][64] = 32768 B
  bf16* Bs = (bf16*)(smem + 32768);    // [2][64][64]  = 16384 B
  float* tileO = (float*)smem;         // [128][65] f32 = 33280 B (aliases, used after loop)
  const int K = 896;
  int lg = (blockIdx.x & 7) * 72 + (blockIdx.x >> 3);   // bijective XCD-chunk remap (576=8*72)
  int bxi = lg % 18, byi = lg / 18;
  int n0 = bxi * 64, m0 = byi * 128;
  int tid = threadIdx.x;
  int wid = tid >> 6, lane = tid & 63;
  int lr = lane & 15, lh = lane >> 4;
  int wr = wid >> 1, wc = wid & 1;
  int lrow8 = lane >> 3, lchk = lane & 7;   // staging: 8 rows x 8 chunks per segment
  f32x4 acc[4][2] = {};

  auto stage = [&](int buf, int k0) {
#pragma unroll
    for (int i = 0; i < 4; ++i) {
      int seg = i * 4 + wid;               // 0..15
      int r = seg * 8 + lrow8;
      gload_lds16(A + (size_t)(m0 + r) * K + k0 + ((lchk ^ (r & 7)) << 3),
                  As + buf * 8192 + seg * 512);
    }
#pragma unroll
    for (int i = 0; i < 2; ++i) {
      int seg = i * 4 + wid;               // 0..7
      int r = seg * 8 + lrow8;
      gload_lds16(Bt + (size_t)(n0 + r) * K + k0 + ((lchk ^ (r & 7)) << 3),
                  Bs + buf * 4096 + seg * 512);
    }
  };

  stage(0, 0);
  __syncthreads();
  const int nk = K >> 6;   // 14
  int cur = 0;
  for (int t = 0; t < nk; ++t) {
    if (t + 1 < nk) stage(cur ^ 1, (t + 1) << 6);
#pragma unroll
    for (int kk = 0; kk < 2; ++kk) {
      bf16x8 am[4], bn[2];
#pragma unroll
      for (int mf = 0; mf < 4; ++mf) {
        int row = wr * 64 + mf * 16 + lr;
        am[mf] = *reinterpret_cast<const bf16x8*>(
            (char*)(As + cur * 8192 + row * 64) + ((kk * 64 + lh * 16) ^ ((row & 7) << 4)));
      }
#pragma unroll
      for (int nf = 0; nf < 2; ++nf) {
        int row = wc * 32 + nf * 16 + lr;
        bn[nf] = *reinterpret_cast<const bf16x8*>(
            (char*)(Bs + cur * 4096 + row * 64) + ((kk * 64 + lh * 16) ^ ((row & 7) << 4)));
      }
      __builtin_amdgcn_s_setprio(1);
#pragma unroll
      for (int mf = 0; mf < 4; ++mf)
#pragma unroll
        for (int nf = 0; nf < 2; ++nf)
          acc[mf][nf] = mfma16(am[mf], bn[nf], acc[mf][nf]);
      __builtin_amdgcn_s_setprio(0);
    }
    __syncthreads();   // also makes As/Bs dead after the last iteration
    cur ^= 1;
  }

  // ---- store acc (+bias) to LDS f32 tile ----
#pragma unroll
  for (int nf = 0; nf < 2; ++nf) {
    int col = wc * 32 + nf * 16 + lr;
    float bb = bias[n0 + col];
#pragma unroll
    for (int mf = 0; mf < 4; ++mf) {
      int row0 = wr * 64 + mf * 16 + lh * 4;
#pragma unroll
      for (int j = 0; j < 4; ++j)
        tileO[(row0 + j) * 65 + col] = acc[mf][nf][j] + bb;
    }
  }
  __syncthreads();

  const float QSCALE = 0.125f * 1.44269504088896f;  // 1/sqrt(64) * log2(e)
  int b = byi >> 4;
  int s0 = (byi & 15) * 128;
  int bx = bxi;
  if (bx < 14) {
    // Q head: rope + scale, plain [b][h][s][64]
    int r2 = tid >> 1, half = tid & 1;
    int s = s0 + r2;
    const float* tr = trig + (size_t)s * 64;
    size_t base = ((size_t)(b * NHEADS + bx) * S_LEN + s) * HDIM;
    bf16x8 o1[2], o2[2];
#pragma unroll
    for (int v = 0; v < 2; ++v)
#pragma unroll
      for (int p = 0; p < 8; ++p) {
        int d = half * 16 + v * 8 + p;
        float c = tr[d], sn = tr[32 + d];
        float v1 = tileO[r2 * 65 + d], v2 = tileO[r2 * 65 + d + 32];
        o1[v][p] = (bf16)((v1 * c - v2 * sn) * QSCALE);
        o2[v][p] = (bf16)((v2 * c + v1 * sn) * QSCALE);
      }
    *(bf16x8*)(Qb + base + half * 16)      = o1[0];
    *(bf16x8*)(Qb + base + half * 16 + 8)  = o1[1];
    *(bf16x8*)(Qb + base + 32 + half * 16)     = o2[0];
    *(bf16x8*)(Qb + base + 32 + half * 16 + 8) = o2[1];
  } else if (bx < 16) {
    // K head: rope + XOR swizzle d ^ (((s&7)^((s>>3)&1))<<3)
    int kh = bx - 14;
    int r2 = tid >> 1, half = tid & 1;
    int s = s0 + r2;
    const float* tr = trig + (size_t)s * 64;
    int sw = (((s & 7) ^ ((s >> 3) & 1)) << 3);
    size_t base = ((size_t)(b * NKVH + kh) * S_LEN + s) * HDIM;
#pragma unroll
    for (int p = 0; p < 16; ++p) {
      int d = half * 16 + p;
      float c = tr[d], sn = tr[32 + d];
      float v1 = tileO[r2 * 65 + d], v2 = tileO[r2 * 65 + d + 32];
      Kb[base + (d ^ sw)]        = (bf16)(v1 * c - v2 * sn);
      Kb[base + ((d + 32) ^ sw)] = (bf16)(v2 * c + v1 * sn);
    }
  } else {
    // V head: transpose to [b][kv][64][S], col (s&63) ^ ((d&7)<<3)
    int kh = bx - 16;
    int d = tid & 63, seg = tid >> 6;
    size_t vbase = ((size_t)(b * NKVH + kh) * HDIM + d) * S_LEN;
    int c8 = (d & 7) << 3;
#pragma unroll
    for (int g = 0; g < 4; ++g) {
      int sl = seg * 32 + g * 8;   // aligned-8 s_local run
      bf16x8 w;
#pragma unroll
      for (int p = 0; p < 8; ++p)
        w[p] = (bf16)tileO[(sl + p) * 65 + d];
      int s = s0 + sl;
      int col = (s & ~63) | (((s & 63) ^ c8) & ~7);
      *(bf16x8*)(Vt + vbase + col) = w;
    }
  }
}

// ---------------- GEMM: C[M][N] = A[M][K]*Bt[N][K]^T (f32 out, BK=64, XCD-chunked) ----------------
// 1D grid 448 = 8*56; logical = (orig%8)*56 + orig/8; bx = logical%14, by = logical/14.
__global__ __launch_bounds__(256) void gemm_bt_kernel(const bf16* __restrict__ A,
                                                      const bf16* __restrict__ Bt,
                                                      float* __restrict__ C,
                                                      int M, int N, int K) {
  __shared__ __align__(16) bf16 As[2][128][64];
  __shared__ __align__(16) bf16 Bs[2][64][64];
  int lg = (blockIdx.x & 7) * 56 + (blockIdx.x >> 3);
  int bxi = lg % 14, byi = lg / 14;
  int n0 = bxi * 64, m0 = byi * 128;
  int tid = threadIdx.x;
  int wid = tid >> 6, lane = tid & 63;
  int lr = lane & 15, lh = lane >> 4;
  int wr = wid >> 1, wc = wid & 1;
  int lrow8 = lane >> 3, lchk = lane & 7;
  f32x4 acc[4][2] = {};

  auto stage = [&](int buf, int k0) {
#pragma unroll
    for (int i = 0; i < 4; ++i) {
      int seg = i * 4 + wid;
      int r = seg * 8 + lrow8;
      gload_lds16(A + (size_t)(m0 + r) * K + k0 + ((lchk ^ (r & 7)) << 3),
                  &As[buf][0][0] + seg * 512);
    }
#pragma unroll
    for (int i = 0; i < 2; ++i) {
      int seg = i * 4 + wid;
      int r = seg * 8 + lrow8;
      gload_lds16(Bt + (size_t)(n0 + r) * K + k0 + ((lchk ^ (r & 7)) << 3),
                  &Bs[buf][0][0] + seg * 512);
    }
  };

  stage(0, 0);
  __syncthreads();
  int nk = K >> 6;
  int cur = 0;
  for (int t = 0; t < nk; ++t) {
    if (t + 1 < nk) stage(cur ^ 1, (t + 1) << 6);
#pragma unroll
    for (int kk = 0; kk < 2; ++kk) {
      bf16x8 am[4], bn[2];
#pragma unroll
      for (int mf = 0; mf < 4; ++mf) {
        int row = wr * 64 + mf * 16 + lr;
        am[mf] = *reinterpret_cast<const bf16x8*>(
            (char*)&As[cur][row][0] + ((kk * 64 + lh * 16) ^ ((row & 7) << 4)));
      }
#pragma unroll
      for (int nf = 0; nf < 2; ++nf) {
        int row = wc * 32 + nf * 16 + lr;
        bn[nf] = *reinterpret_cast<const bf16x8*>(
            (char*)&Bs[cur][row][0] + ((kk * 64 + lh * 16) ^ ((row & 7) << 4)));
      }
      __builtin_amdgcn_s_setprio(1);
#pragma unroll
      for (int mf = 0; mf < 4; ++mf)
#pragma unroll
        for (int nf = 0; nf < 2; ++nf)
          acc[mf][nf] = mfma16(am[mf], bn[nf], acc[mf][nf]);
      __builtin_amdgcn_s_setprio(0);
    }
    __syncthreads();
    cur ^= 1;
  }

#pragma unroll
  for (int nf = 0; nf < 2; ++nf) {
    int col = n0 + wc * 32 + nf * 16 + lr;
#pragma unroll
    for (int mf = 0; mf < 4; ++mf) {
      int row0 = m0 + wr * 64 + mf * 16 + lh * 4;
#pragma unroll
      for (int j = 0; j < 4; ++j)
        C[(size_t)(row0 + j) * N + col] = acc[mf][nf][j];
    }
  }
}

// ---------------- flash attention: shuffle-free steady-state softmax (no setprio) ----------------
// Opart: [28][40][128][64] bf16, Oml: [28][40][128][2] f32 (m, l in log2 domain)
__global__ __launch_bounds__(256, 4) void attn_kernel(const bf16* __restrict__ Qb,
                                                      const bf16* __restrict__ Kb,
                                                      const bf16* __restrict__ Vt,
                                                      bf16* __restrict__ Opart,
                                                      float* __restrict__ Oml,
                                                      bf16* __restrict__ Ob) {
  int blk = blockIdx.x;
  int c = chunk_order[blk % NCHUNK], bh = blk / NCHUNK;
  int qt, ch;
  chunk_map(c, qt, ch);
  int h = bh % NHEADS, b = bh / NHEADS;
  int q0 = qt * 128;
  int kv = h / 7;
  int kc0 = ch * 512;
  int kend = min(kc0 + 512, q0 + 128);
  int nt = (kend - kc0) >> 6;
  int tid = threadIdx.x, wid = tid >> 6, lane = tid & 63;
  int lr = lane & 15, lh = lane >> 4;
  int swk = (lr & 7) << 4;   // byte XOR for V LDS reads

  const bf16* Qp = Qb + ((size_t)(b * NHEADS + h) * S_LEN + q0 + wid * 32) * HDIM;
  const char* KpB = (const char*)(Kb + (size_t)(b * NKVH + kv) * S_LEN * HDIM);
  const char* VpB = (const char*)(Vt + (size_t)(b * NKVH + kv) * HDIM * S_LEN);

  __shared__ __align__(16) bf16 Ks[2][4096];
  __shared__ __align__(16) bf16 Vs[2][4096];

  bf16x8 aq[2][2];
#pragma unroll
  for (int f = 0; f < 2; ++f)
#pragma unroll
    for (int kk = 0; kk < 2; ++kk)
      aq[f][kk] = *reinterpret_cast<const bf16x8*>(
          Qp + (size_t)(f * 16 + lr) * HDIM + kk * 32 + lh * 8);

  float m[2] = {-3.0e38f, -3.0e38f}, l[2] = {0.f, 0.f};
  f32x4 o[2][4] = {};

  auto stage = [&](int buf, int kv0) {
#pragma unroll
    for (int i = 0; i < 2; ++i) {
      gload_lds16b(KpB + (size_t)kv0 * 128 + wid * 2048 + i * 1024 + lane * 16,
                   &Ks[buf][wid * 1024 + i * 512]);
      int d = wid * 16 + i * 8 + (lane >> 3);
      gload_lds16b(VpB + (size_t)d * (S_LEN * 2) + kv0 * 2 + (lane & 7) * 16,
                   &Vs[buf][wid * 1024 + i * 512]);
    }
  };

  stage(0, kc0);
  __syncthreads();

  int qf0 = q0 + wid * 32;
  int cur = 0;
  for (int t = 0; t < nt; ++t) {
    int kv0 = kc0 + (t << 6);
    // ---- swapped QK^T: sacc[f][nf][j] = S[q = qf0+f*16+lr][k = kv0+g(nf, lh*4+j)] ----
    const char* KsB = (const char*)&Ks[cur][0];
    f32x4 sacc[2][4] = {};
#pragma unroll
    for (int nf = 0; nf < 4; ++nf) {
      int rowk = 8 * (lr >> 2) + (lr & 3) + ((nf & 1) << 2) + ((nf >> 1) << 5);
      int rsw = (((rowk & 7) ^ ((rowk >> 3) & 1)) << 4);
#pragma unroll
      for (int kk = 0; kk < 2; ++kk) {
        bf16x8 kb = *(const bf16x8*)(KsB + rowk * 128 + ((kk * 64 + lh * 16) ^ rsw));
        sacc[0][nf] = mfma16(kb, aq[0][kk], sacc[0][nf]);
        sacc[1][nf] = mfma16(kb, aq[1][kk], sacc[1][nf]);
      }
    }
    if (t + 1 < nt) stage(cur ^ 1, kv0 + 64);

    // ---- mask (wave-uniform skip) + LANE-LOCAL max (no shuffles) ----
    float lmax[2];
#pragma unroll
    for (int f = 0; f < 2; ++f) {
      int qg = qf0 + f * 16 + lr;
      if (kv0 + 63 > qf0 + f * 16) {
#pragma unroll
        for (int nf = 0; nf < 4; ++nf) {
          int kb0 = kv0 + ((nf & 1) << 2) + ((nf >> 1) << 5) + (lh << 3);
#pragma unroll
          for (int j = 0; j < 4; ++j)
            if (kb0 + j > qg) sacc[f][nf][j] = -3.0e38f;
        }
      }
      f32x4 m01, m23;
#pragma unroll
      for (int j = 0; j < 4; ++j) {
        m01[j] = fmaxf(sacc[f][0][j], sacc[f][1][j]);
        m23[j] = fmaxf(sacc[f][2][j], sacc[f][3][j]);
      }
      f32x4 m4;
#pragma unroll
      for (int j = 0; j < 4; ++j) m4[j] = fmaxf(m01[j], m23[j]);
      lmax[f] = fmaxf(fmaxf(m4[0], m4[1]), fmaxf(m4[2], m4[3]));
    }
    // ---- defer-max guard: cross-lane reduce + rescale only on growth > 8 ----
    float g = fmaxf(lmax[0] - m[0], lmax[1] - m[1]);
    if (!__all(g <= 8.0f)) {
#pragma unroll
      for (int f = 0; f < 2; ++f) {
        float mxl = fmaxf(lmax[f], __shfl_xor(lmax[f], 16));
        mxl = fmaxf(mxl, __shfl_xor(mxl, 32));
        float mn = fmaxf(m[f], mxl);
        float al = exp2f(m[f] - mn);
        m[f] = mn;
        l[f] *= al;
        f32x4 av;
#pragma unroll
        for (int j = 0; j < 4; ++j) av[j] = __shfl(al, (lh << 2) + j);
#pragma unroll
        for (int nf = 0; nf < 4; ++nf) o[f][nf] *= av;
      }
    }
    // ---- exp2 + LANE-PARTIAL sum (no shuffles) + in-register P pack ----
    bf16x8 pa[2][2];
#pragma unroll
    for (int f = 0; f < 2; ++f) {
      f32x4 rs4 = {0.f, 0.f, 0.f, 0.f};
#pragma unroll
      for (int nf = 0; nf < 4; ++nf) {
#pragma unroll
        for (int j = 0; j < 4; ++j)
          sacc[f][nf][j] = exp2f(sacc[f][nf][j] - m[f]);
        rs4 += sacc[f][nf];
      }
      l[f] += (rs4[0] + rs4[1]) + (rs4[2] + rs4[3]);   // lane-partial
#pragma unroll
      for (int kk = 0; kk < 2; ++kk) {
        u32x4 w;
        w[0] = cvtpk(sacc[f][2 * kk][0], sacc[f][2 * kk][1]);
        w[1] = cvtpk(sacc[f][2 * kk][2], sacc[f][2 * kk][3]);
        w[2] = cvtpk(sacc[f][2 * kk + 1][0], sacc[f][2 * kk + 1][1]);
        w[3] = cvtpk(sacc[f][2 * kk + 1][2], sacc[f][2 * kk + 1][3]);
        pa[f][kk] = __builtin_bit_cast(bf16x8, w);
      }
    }
    // ---- PV ----
    const char* VsB = (const char*)&Vs[cur][0];
#pragma unroll
    for (int nf = 0; nf < 4; ++nf) {
#pragma unroll
      for (int kk = 0; kk < 2; ++kk) {
        bf16x8 vb = *(const bf16x8*)(VsB + (nf * 16 + lr) * 128 + ((kk * 64 + lh * 16) ^ swk));
        o[0][nf] = mfma16(pa[0][kk], vb, o[0][nf]);
        o[1][nf] = mfma16(pa[1][kk], vb, o[1][nf]);
      }
    }
    __syncthreads();   // drains staging vmcnt + protects buffer flip
    cur ^= 1;
  }

  // complete the row-sums: combine the 4 lane-partials of each row (once per chunk)
#pragma unroll
  for (int f = 0; f < 2; ++f) {
    l[f] += __shfl_xor(l[f], 16);
    l[f] += __shfl_xor(l[f], 32);
  }

  if (qt < 4) {
    // single-chunk q-tile: write normalized output directly to Ob (skip combine).
    // l[f] is lane-local to q-row lr; o[f][nf][j] lives at row lh*4+j -> transpose.
#pragma unroll
    for (int f = 0; f < 2; ++f) {
      f32x4 inv4;
#pragma unroll
      for (int j = 0; j < 4; ++j)
        inv4[j] = 1.0f / __shfl(l[f], (lh << 2) + j);
#pragma unroll
      for (int nf = 0; nf < 4; ++nf) {
        int col = h * 64 + nf * 16 + lr;
#pragma unroll
        for (int j = 0; j < 4; ++j) {
          int rloc = wid * 32 + f * 16 + (lh << 2) + j;
          Ob[((size_t)(b * S_LEN) + q0 + rloc) * HID + col] = (bf16)(o[f][nf][j] * inv4[j]);
        }
      }
    }
    return;
  }

  // epilogue: write unnormalized partial O (bf16) + per-row (m, l)
  size_t pbase = ((size_t)bh * NCHUNK + c) * (128 * 64);
#pragma unroll
  for (int f = 0; f < 2; ++f)
#pragma unroll
    for (int nf = 0; nf < 4; ++nf) {
      int col = nf * 16 + lr;
#pragma unroll
      for (int j = 0; j < 4; ++j) {
        int rloc = wid * 32 + f * 16 + (lh << 2) + j;
        Opart[pbase + (size_t)rloc * 64 + col] = (bf16)o[f][nf][j];
      }
    }
  if (lane < 16) {
    size_t mbase = ((size_t)bh * NCHUNK + c) * 128;
#pragma unroll
    for (int f = 0; f < 2; ++f) {
      int rloc = wid * 32 + f * 16 + lane;
      Oml[(mbase + rloc) * 2]     = m[f];
      Oml[(mbase + rloc) * 2 + 1] = l[f];
    }
  }
}

// ---------------- combine partials (qt >= 4 only; m in log2 domain) ----------------
__global__ __launch_bounds__(256) void combine_kernel(const bf16* __restrict__ Opart,
                                                      const float* __restrict__ Oml,
                                                      bf16* __restrict__ Ob) {
  int blk = blockIdx.x;            // bh*12 + (qt-4)
  int qt = 4 + blk % 12, bh = blk / 12;
  int h = bh % NHEADS, b = bh / NHEADS;
  int a = qt >> 2, bb = qt & 3;
  int nch = a + 1;
  int coff = (a + 1) * (2 * a + bb);
  int t = threadIdx.x;
  int row = t >> 1, cg = t & 1;    // 32 cols per thread

  float M = -__builtin_inff();
  for (int i = 0; i < nch; ++i)
    M = fmaxf(M, Oml[(((size_t)bh * NCHUNK + coff + i) * 128 + row) * 2]);
  float L = 0.f;
  for (int i = 0; i < nch; ++i) {
    size_t mb = (((size_t)bh * NCHUNK + coff + i) * 128 + row) * 2;
    L += exp2f(Oml[mb] - M) * Oml[mb + 1];
  }
  float acc[32];
#pragma unroll
  for (int k = 0; k < 32; ++k) acc[k] = 0.f;
  for (int i = 0; i < nch; ++i) {
    size_t mb = (((size_t)bh * NCHUNK + coff + i) * 128 + row) * 2;
    float w = exp2f(Oml[mb] - M);
    const bf16* src = Opart + (((size_t)bh * NCHUNK + coff + i) * 128 + row) * 64 + cg * 32;
#pragma unroll
    for (int v = 0; v < 4; ++v) {
      bf16x8 x = *reinterpret_cast<const bf16x8*>(src + v * 8);
#pragma unroll
      for (int k = 0; k < 8; ++k) acc[v * 8 + k] += w * (float)x[k];
    }
  }
  float inv = 1.0f / L;
  bf16* dst = Ob + ((size_t)(b * S_LEN) + qt * 128 + row) * HID + h * 64 + cg * 32;
#pragma unroll
  for (int v = 0; v < 4; ++v) {
    bf16x8 r;
#pragma unroll
    for (int k = 0; k < 8; ++k) r[k] = (bf16)(acc[v * 8 + k] * inv);
    *reinterpret_cast<bf16x8*>(dst + v * 8) = r;
  }
}

// ---------------- launch ----------------
extern "C" void kernel_launch(void* const* d_in, const int* in_sizes, int n_in,
                              void* d_out, int out_size, void* d_ws, size_t ws_size,
                              hipStream_t stream) {
  (void)in_sizes; (void)n_in; (void)out_size; (void)ws_size;
  const float* X  = (const float*)d_in[0];
  const float* Wq = (const float*)d_in[2];
  const float* bq = (const float*)d_in[3];
  const float* Wk = (const float*)d_in[4];
  const float* bk = (const float*)d_in[5];
  const float* Wv = (const float*)d_in[6];
  const float* bv = (const float*)d_in[7];
  const float* Wo = (const float*)d_in[8];
  float* OUT = (float*)d_out;

  char* ws = (char*)d_ws;
  bf16*  Xb    = (bf16*)(ws);                 // 4096*896*2  = 7,340,032
  bf16*  WqkvT = (bf16*)(ws + 7340032);       // 1152*896*2  = 2,064,384
  bf16*  WoT   = (bf16*)(ws + 9404416);       // 896*896*2   = 1,605,632
  float* biasq = (float*)(ws + 11010048);     // 1152*4
  bf16*  Opart = (bf16*)(ws + 11014656);      // 28*40*128*64*2 = 18,350,080
  float* trig  = (float*)(ws + 29364736);     // 2048*64*4 = 524,288 (ends 29,889,024)
  bf16*  Qbuf  = (bf16*)(ws + 29889024);      // 4096*896*2
  bf16*  Kbuf  = (bf16*)(ws + 37229056);      // 2*2*2048*64*2
  bf16*  Vbuf  = (bf16*)(ws + 38277632);      // 2*2*64*2048*2  (ends 39,326,208)
  float* Oml   = (float*)(ws + 7340032);      // reuse WqkvT region after GEMM1 (1,146,880)
  bf16*  Obuf  = Xb;                          // reuse (Xb dead after GEMM1)

  prep_kernel<<<5637, 256, 0, stream>>>(X, Xb, Wq, Wk, Wv, Wo, WqkvT, WoT,
                                        bq, bk, bv, biasq, trig);
  gemm_qkv_kernel<<<576, 256, 0, stream>>>(Xb, WqkvT, biasq, trig,
                                           Qbuf, Kbuf, Vbuf);
  attn_kernel<<<28 * NCHUNK, 256, 0, stream>>>(Qbuf, Kbuf, Vbuf, Opart, Oml, Obuf);
  combine_kernel<<<28 * 12, 256, 0, stream>>>(Opart, Oml, Obuf);
  gemm_bt_kernel<<<448, 256, 0, stream>>>(Obuf, WoT, OUT, 4096, 896, 896);
}

// Round 19
// 94.747 us; speedup vs baseline: 1.0701x; 1.0038x over previous
//
#include <hip/hip_runtime.h>

#define S_LEN 2048
#define NHEADS 14
#define NKVH 2
#define HDIM 64
#define HID 896
#define NQKV 1152
#define NCHUNK 40   // per bh: sum over 16 q-blocks(128 rows) of ceil(128*(qt+1)/512)

typedef __bf16 bf16;
typedef __bf16 bf16x4 __attribute__((ext_vector_type(4)));
typedef __bf16 bf16x8 __attribute__((ext_vector_type(8)));
typedef float f32x4 __attribute__((ext_vector_type(4)));
typedef unsigned int u32x4 __attribute__((ext_vector_type(4)));

__device__ inline f32x4 mfma16(bf16x8 a, bf16x8 b, f32x4 c) {
  return __builtin_amdgcn_mfma_f32_16x16x32_bf16(a, b, c, 0, 0, 0);
}

__device__ inline void gload_lds16(const bf16* g, bf16* l) {
  __builtin_amdgcn_global_load_lds(
      (const __attribute__((address_space(1))) void*)g,
      (__attribute__((address_space(3))) void*)l, 16, 0, 0);
}
__device__ inline void gload_lds16b(const void* g, void* l) {
  __builtin_amdgcn_global_load_lds(
      (const __attribute__((address_space(1))) void*)g,
      (__attribute__((address_space(3))) void*)l, 16, 0, 0);
}

__device__ inline unsigned cvtpk(float lo, float hi) {
  unsigned r;
  asm("v_cvt_pk_bf16_f32 %0, %1, %2" : "=v"(r) : "v"(lo), "v"(hi));
  return r;
}

// chunk index c (0..39) -> (q-block qt 0..15, chunk-within ch); nch(qt)=(qt>>2)+1
__device__ inline void chunk_map(int c, int& qt, int& ch) {
  if (c < 4)       { qt = c;                ch = 0; }
  else if (c < 12) { qt = 4 + ((c - 4) >> 1); ch = (c - 4) & 1; }
  else if (c < 24) { int d = c - 12; qt = 8 + d / 3; ch = d % 3; }
  else             { int d = c - 24; qt = 12 + (d >> 2); ch = d & 3; }
}

// chunks sorted by tile-length descending (28 eights, 4 sixes, 4 fours, 4 twos):
// per-CU length-sums equalize (snake-LPT) while keeping bh-major locality.
__device__ const int chunk_order[NCHUNK] = {
  36, 37, 38, 39, 32, 33, 34, 28, 29, 30, 24, 25, 26, 21, 22, 23,
  18, 19, 15, 16, 12, 13, 10, 11, 8, 6, 4, 3,
  35, 20, 9, 2,   // sixes
  31, 17, 7, 1,   // fours
  27, 14, 5, 0    // twos
};

// ---------------- fused prep: cast X, transpose-cast all W, pack bias, trig table ----------------
__global__ __launch_bounds__(256) void prep_kernel(
    const float* __restrict__ X, bf16* __restrict__ Xb,
    const float* __restrict__ Wq, const float* __restrict__ Wk,
    const float* __restrict__ Wv, const float* __restrict__ Wo,
    bf16* __restrict__ WqkvT, bf16* __restrict__ WoT,
    const float* __restrict__ bq, const float* __restrict__ bk,
    const float* __restrict__ bv, float* __restrict__ biasq,
    float* __restrict__ trig) {
  __shared__ float tile[32][33];
  int blk = blockIdx.x;
  int tid = threadIdx.x;
  if (blk < 3584) {
    int i = blk * 256 + tid;
    if (i < 917504) {
      float4 v = reinterpret_cast<const float4*>(X)[i];
      bf16x4 o;
      o[0] = (bf16)v.x; o[1] = (bf16)v.y; o[2] = (bf16)v.z; o[3] = (bf16)v.w;
      reinterpret_cast<bf16x4*>(Xb)[i] = o;
    }
    return;
  }
  if (blk < 5376) {
    int t = blk - 3584;
    const float* W; bf16* dst; int N, bx, by;
    if (t < 784)       { W = Wq; dst = WqkvT;                      N = 896; bx = t % 28;          by = t / 28; }
    else if (t < 896)  { int u = t - 784;  W = Wk; dst = WqkvT + (size_t)896 * 896;  N = 128; bx = u % 4; by = u / 4; }
    else if (t < 1008) { int u = t - 896;  W = Wv; dst = WqkvT + (size_t)1024 * 896; N = 128; bx = u % 4; by = u / 4; }
    else               { int u = t - 1008; W = Wo; dst = WoT;      N = 896; bx = u % 28;          by = u / 28; }
    int n0 = bx * 32, k0 = by * 32;
    int tx = tid & 31, ty = tid >> 5;  // 32 x 8
#pragma unroll
    for (int j = 0; j < 32; j += 8)
      tile[ty + j][tx] = W[(size_t)(k0 + ty + j) * N + n0 + tx];
    __syncthreads();
#pragma unroll
    for (int j = 0; j < 32; j += 8)
      dst[(size_t)(n0 + ty + j) * HID + k0 + tx] = (bf16)tile[tx][ty + j];
    return;
  }
  if (blk < 5381) {
    int i = (blk - 5376) * 256 + tid;
    if (i < 896) biasq[i] = bq[i];
    else if (i < 1024) biasq[i] = bk[i - 896];
    else if (i < 1152) biasq[i] = bv[i - 1024];
    return;
  }
  // trig table: [2048][64] = cos at [s][d], sin at [s][32+d], d=0..31
  {
    int ti = blk - 5381;                 // 0..255
    int s = ti * 8 + (tid >> 5);
    int d = tid & 31;
    float inv = expf(-(float)d * (13.815510557964274f / 32.0f));  // 1e6^(-d/32)
    float a = (float)s * inv;
    float c, si;
    sincosf(a, &si, &c);
    trig[(size_t)s * 64 + d] = c;
    trig[(size_t)s * 64 + 32 + d] = si;
  }
}

// ---------------- GEMM1 fused with RoPE + Q/K/V layout (BK=64, swizzled LDS, XCD-chunked) ----------------
__global__ __launch_bounds__(256) void gemm_qkv_kernel(const bf16* __restrict__ A,
                                                       const bf16* __restrict__ Bt,
                                                       const float* __restrict__ bias,
                                                       const float* __restrict__ trig,
                                                       bf16* __restrict__ Qb,
                                                       bf16* __restrict__ Kb,
                                                       bf16* __restrict__ Vt) {
  __shared__ __align__(16) char smem[49152];
  bf16* As = (bf16*)smem;              // [2][128][64] = 32768 B
  bf16* Bs = (bf16*)(smem + 32768);    // [2][64][64]  = 16384 B
  float* tileO = (float*)smem;         // [128][65] f32 = 33280 B (aliases, used after loop)
  const int K = 896;
  int lg = (blockIdx.x & 7) * 72 + (blockIdx.x >> 3);   // bijective XCD-chunk remap (576=8*72)
  int bxi = lg % 18, byi = lg / 18;
  int n0 = bxi * 64, m0 = byi * 128;
  int tid = threadIdx.x;
  int wid = tid >> 6, lane = tid & 63;
  int lr = lane & 15, lh = lane >> 4;
  int wr = wid >> 1, wc = wid & 1;
  int lrow8 = lane >> 3, lchk = lane & 7;   // staging: 8 rows x 8 chunks per segment
  f32x4 acc[4][2] = {};

  auto stage = [&](int buf, int k0) {
#pragma unroll
    for (int i = 0; i < 4; ++i) {
      int seg = i * 4 + wid;               // 0..15
      int r = seg * 8 + lrow8;
      gload_lds16(A + (size_t)(m0 + r) * K + k0 + ((lchk ^ (r & 7)) << 3),
                  As + buf * 8192 + seg * 512);
    }
#pragma unroll
    for (int i = 0; i < 2; ++i) {
      int seg = i * 4 + wid;               // 0..7
      int r = seg * 8 + lrow8;
      gload_lds16(Bt + (size_t)(n0 + r) * K + k0 + ((lchk ^ (r & 7)) << 3),
                  Bs + buf * 4096 + seg * 512);
    }
  };

  stage(0, 0);
  __syncthreads();
  const int nk = K >> 6;   // 14
  int cur = 0;
  for (int t = 0; t < nk; ++t) {
    if (t + 1 < nk) stage(cur ^ 1, (t + 1) << 6);
#pragma unroll
    for (int kk = 0; kk < 2; ++kk) {
      bf16x8 am[4], bn[2];
#pragma unroll
      for (int mf = 0; mf < 4; ++mf) {
        int row = wr * 64 + mf * 16 + lr;
        am[mf] = *reinterpret_cast<const bf16x8*>(
            (char*)(As + cur * 8192 + row * 64) + ((kk * 64 + lh * 16) ^ ((row & 7) << 4)));
      }
#pragma unroll
      for (int nf = 0; nf < 2; ++nf) {
        int row = wc * 32 + nf * 16 + lr;
        bn[nf] = *reinterpret_cast<const bf16x8*>(
            (char*)(Bs + cur * 4096 + row * 64) + ((kk * 64 + lh * 16) ^ ((row & 7) << 4)));
      }
      __builtin_amdgcn_s_setprio(1);
#pragma unroll
      for (int mf = 0; mf < 4; ++mf)
#pragma unroll
        for (int nf = 0; nf < 2; ++nf)
          acc[mf][nf] = mfma16(am[mf], bn[nf], acc[mf][nf]);
      __builtin_amdgcn_s_setprio(0);
    }
    __syncthreads();   // also makes As/Bs dead after the last iteration
    cur ^= 1;
  }

  // ---- store acc (+bias) to LDS f32 tile ----
#pragma unroll
  for (int nf = 0; nf < 2; ++nf) {
    int col = wc * 32 + nf * 16 + lr;
    float bb = bias[n0 + col];
#pragma unroll
    for (int mf = 0; mf < 4; ++mf) {
      int row0 = wr * 64 + mf * 16 + lh * 4;
#pragma unroll
      for (int j = 0; j < 4; ++j)
        tileO[(row0 + j) * 65 + col] = acc[mf][nf][j] + bb;
    }
  }
  __syncthreads();

  const float QSCALE = 0.125f * 1.44269504088896f;  // 1/sqrt(64) * log2(e)
  int b = byi >> 4;
  int s0 = (byi & 15) * 128;
  int bx = bxi;
  if (bx < 14) {
    // Q head: rope + scale, plain [b][h][s][64]
    int r2 = tid >> 1, half = tid & 1;
    int s = s0 + r2;
    const float* tr = trig + (size_t)s * 64;
    size_t base = ((size_t)(b * NHEADS + bx) * S_LEN + s) * HDIM;
    bf16x8 o1[2], o2[2];
#pragma unroll
    for (int v = 0; v < 2; ++v)
#pragma unroll
      for (int p = 0; p < 8; ++p) {
        int d = half * 16 + v * 8 + p;
        float c = tr[d], sn = tr[32 + d];
        float v1 = tileO[r2 * 65 + d], v2 = tileO[r2 * 65 + d + 32];
        o1[v][p] = (bf16)((v1 * c - v2 * sn) * QSCALE);
        o2[v][p] = (bf16)((v2 * c + v1 * sn) * QSCALE);
      }
    *(bf16x8*)(Qb + base + half * 16)      = o1[0];
    *(bf16x8*)(Qb + base + half * 16 + 8)  = o1[1];
    *(bf16x8*)(Qb + base + 32 + half * 16)     = o2[0];
    *(bf16x8*)(Qb + base + 32 + half * 16 + 8) = o2[1];
  } else if (bx < 16) {
    // K head: rope + XOR swizzle d ^ (((s&7)^((s>>3)&1))<<3)
    int kh = bx - 14;
    int r2 = tid >> 1, half = tid & 1;
    int s = s0 + r2;
    const float* tr = trig + (size_t)s * 64;
    int sw = (((s & 7) ^ ((s >> 3) & 1)) << 3);
    size_t base = ((size_t)(b * NKVH + kh) * S_LEN + s) * HDIM;
#pragma unroll
    for (int p = 0; p < 16; ++p) {
      int d = half * 16 + p;
      float c = tr[d], sn = tr[32 + d];
      float v1 = tileO[r2 * 65 + d], v2 = tileO[r2 * 65 + d + 32];
      Kb[base + (d ^ sw)]        = (bf16)(v1 * c - v2 * sn);
      Kb[base + ((d + 32) ^ sw)] = (bf16)(v2 * c + v1 * sn);
    }
  } else {
    // V head: transpose to [b][kv][64][S], col (s&63) ^ ((d&7)<<3)
    int kh = bx - 16;
    int d = tid & 63, seg = tid >> 6;
    size_t vbase = ((size_t)(b * NKVH + kh) * HDIM + d) * S_LEN;
    int c8 = (d & 7) << 3;
#pragma unroll
    for (int g = 0; g < 4; ++g) {
      int sl = seg * 32 + g * 8;   // aligned-8 s_local run
      bf16x8 w;
#pragma unroll
      for (int p = 0; p < 8; ++p)
        w[p] = (bf16)tileO[(sl + p) * 65 + d];
      int s = s0 + sl;
      int col = (s & ~63) | (((s & 63) ^ c8) & ~7);
      *(bf16x8*)(Vt + vbase + col) = w;
    }
  }
}

// ---------------- GEMM: C[M][N] = A[M][K]*Bt[N][K]^T (f32 out, BK=64, XCD-chunked) ----------------
__global__ __launch_bounds__(256) void gemm_bt_kernel(const bf16* __restrict__ A,
                                                      const bf16* __restrict__ Bt,
                                                      float* __restrict__ C,
                                                      int M, int N, int K) {
  __shared__ __align__(16) bf16 As[2][128][64];
  __shared__ __align__(16) bf16 Bs[2][64][64];
  int lg = (blockIdx.x & 7) * 56 + (blockIdx.x >> 3);
  int bxi = lg % 14, byi = lg / 14;
  int n0 = bxi * 64, m0 = byi * 128;
  int tid = threadIdx.x;
  int wid = tid >> 6, lane = tid & 63;
  int lr = lane & 15, lh = lane >> 4;
  int wr = wid >> 1, wc = wid & 1;
  int lrow8 = lane >> 3, lchk = lane & 7;
  f32x4 acc[4][2] = {};

  auto stage = [&](int buf, int k0) {
#pragma unroll
    for (int i = 0; i < 4; ++i) {
      int seg = i * 4 + wid;
      int r = seg * 8 + lrow8;
      gload_lds16(A + (size_t)(m0 + r) * K + k0 + ((lchk ^ (r & 7)) << 3),
                  &As[buf][0][0] + seg * 512);
    }
#pragma unroll
    for (int i = 0; i < 2; ++i) {
      int seg = i * 4 + wid;
      int r = seg * 8 + lrow8;
      gload_lds16(Bt + (size_t)(n0 + r) * K + k0 + ((lchk ^ (r & 7)) << 3),
                  &Bs[buf][0][0] + seg * 512);
    }
  };

  stage(0, 0);
  __syncthreads();
  int nk = K >> 6;
  int cur = 0;
  for (int t = 0; t < nk; ++t) {
    if (t + 1 < nk) stage(cur ^ 1, (t + 1) << 6);
#pragma unroll
    for (int kk = 0; kk < 2; ++kk) {
      bf16x8 am[4], bn[2];
#pragma unroll
      for (int mf = 0; mf < 4; ++mf) {
        int row = wr * 64 + mf * 16 + lr;
        am[mf] = *reinterpret_cast<const bf16x8*>(
            (char*)&As[cur][row][0] + ((kk * 64 + lh * 16) ^ ((row & 7) << 4)));
      }
#pragma unroll
      for (int nf = 0; nf < 2; ++nf) {
        int row = wc * 32 + nf * 16 + lr;
        bn[nf] = *reinterpret_cast<const bf16x8*>(
            (char*)&Bs[cur][row][0] + ((kk * 64 + lh * 16) ^ ((row & 7) << 4)));
      }
      __builtin_amdgcn_s_setprio(1);
#pragma unroll
      for (int mf = 0; mf < 4; ++mf)
#pragma unroll
        for (int nf = 0; nf < 2; ++nf)
          acc[mf][nf] = mfma16(am[mf], bn[nf], acc[mf][nf]);
      __builtin_amdgcn_s_setprio(0);
    }
    __syncthreads();
    cur ^= 1;
  }

#pragma unroll
  for (int nf = 0; nf < 2; ++nf) {
    int col = n0 + wc * 32 + nf * 16 + lr;
#pragma unroll
    for (int mf = 0; mf < 4; ++mf) {
      int row0 = m0 + wr * 64 + mf * 16 + lh * 4;
#pragma unroll
      for (int j = 0; j < 4; ++j)
        C[(size_t)(row0 + j) * N + col] = acc[mf][nf][j];
    }
  }
}

// ---------------- flash attention: shuffle-free softmax, XCD-chunked grid ----------------
// Opart: [28][40][128][64] bf16, Oml: [28][40][128][2] f32 (m, l in log2 domain)
__global__ __launch_bounds__(256, 4) void attn_kernel(const bf16* __restrict__ Qb,
                                                      const bf16* __restrict__ Kb,
                                                      const bf16* __restrict__ Vt,
                                                      bf16* __restrict__ Opart,
                                                      float* __restrict__ Oml,
                                                      bf16* __restrict__ Ob) {
  // XCD-chunk remap (1120 = 8*140): each XCD owns a contiguous run of ~3.5 bh,
  // so each (b,kv) head's 2MB K/V working set stays in one XCD's private L2.
  int blk = (blockIdx.x & 7) * 140 + (blockIdx.x >> 3);
  int c = chunk_order[blk % NCHUNK], bh = blk / NCHUNK;
  int qt, ch;
  chunk_map(c, qt, ch);
  int h = bh % NHEADS, b = bh / NHEADS;
  int q0 = qt * 128;
  int kv = h / 7;
  int kc0 = ch * 512;
  int kend = min(kc0 + 512, q0 + 128);
  int nt = (kend - kc0) >> 6;
  int tid = threadIdx.x, wid = tid >> 6, lane = tid & 63;
  int lr = lane & 15, lh = lane >> 4;
  int swk = (lr & 7) << 4;   // byte XOR for V LDS reads

  const bf16* Qp = Qb + ((size_t)(b * NHEADS + h) * S_LEN + q0 + wid * 32) * HDIM;
  const char* KpB = (const char*)(Kb + (size_t)(b * NKVH + kv) * S_LEN * HDIM);
  const char* VpB = (const char*)(Vt + (size_t)(b * NKVH + kv) * HDIM * S_LEN);

  __shared__ __align__(16) bf16 Ks[2][4096];
  __shared__ __align__(16) bf16 Vs[2][4096];

  auto stage = [&](int buf, int kv0) {
#pragma unroll
    for (int i = 0; i < 2; ++i) {
      gload_lds16b(KpB + (size_t)kv0 * 128 + wid * 2048 + i * 1024 + lane * 16,
                   &Ks[buf][wid * 1024 + i * 512]);
      int d = wid * 16 + i * 8 + (lane >> 3);
      gload_lds16b(VpB + (size_t)d * (S_LEN * 2) + kv0 * 2 + (lane & 7) * 16,
                   &Vs[buf][wid * 1024 + i * 512]);
    }
  };

  stage(0, kc0);   // issue staging first: overlaps with the Q fragment loads below

  bf16x8 aq[2][2];
#pragma unroll
  for (int f = 0; f < 2; ++f)
#pragma unroll
    for (int kk = 0; kk < 2; ++kk)
      aq[f][kk] = *reinterpret_cast<const bf16x8*>(
          Qp + (size_t)(f * 16 + lr) * HDIM + kk * 32 + lh * 8);

  float m[2] = {-3.0e38f, -3.0e38f}, l[2] = {0.f, 0.f};
  f32x4 o[2][4] = {};

  __syncthreads();

  int qf0 = q0 + wid * 32;
  int cur = 0;
  for (int t = 0; t < nt; ++t) {
    int kv0 = kc0 + (t << 6);
    // ---- swapped QK^T: sacc[f][nf][j] = S[q = qf0+f*16+lr][k = kv0+g(nf, lh*4+j)] ----
    const char* KsB = (const char*)&Ks[cur][0];
    f32x4 sacc[2][4] = {};
#pragma unroll
    for (int nf = 0; nf < 4; ++nf) {
      int rowk = 8 * (lr >> 2) + (lr & 3) + ((nf & 1) << 2) + ((nf >> 1) << 5);
      int rsw = (((rowk & 7) ^ ((rowk >> 3) & 1)) << 4);
#pragma unroll
      for (int kk = 0; kk < 2; ++kk) {
        bf16x8 kb = *(const bf16x8*)(KsB + rowk * 128 + ((kk * 64 + lh * 16) ^ rsw));
        sacc[0][nf] = mfma16(kb, aq[0][kk], sacc[0][nf]);
        sacc[1][nf] = mfma16(kb, aq[1][kk], sacc[1][nf]);
      }
    }
    if (t + 1 < nt) stage(cur ^ 1, kv0 + 64);

    // ---- mask (wave-uniform skip) + LANE-LOCAL max (no shuffles) ----
    float lmax[2];
#pragma unroll
    for (int f = 0; f < 2; ++f) {
      int qg = qf0 + f * 16 + lr;
      if (kv0 + 63 > qf0 + f * 16) {
#pragma unroll
        for (int nf = 0; nf < 4; ++nf) {
          int kb0 = kv0 + ((nf & 1) << 2) + ((nf >> 1) << 5) + (lh << 3);
#pragma unroll
          for (int j = 0; j < 4; ++j)
            if (kb0 + j > qg) sacc[f][nf][j] = -3.0e38f;
        }
      }
      f32x4 m01, m23;
#pragma unroll
      for (int j = 0; j < 4; ++j) {
        m01[j] = fmaxf(sacc[f][0][j], sacc[f][1][j]);
        m23[j] = fmaxf(sacc[f][2][j], sacc[f][3][j]);
      }
      f32x4 m4;
#pragma unroll
      for (int j = 0; j < 4; ++j) m4[j] = fmaxf(m01[j], m23[j]);
      lmax[f] = fmaxf(fmaxf(m4[0], m4[1]), fmaxf(m4[2], m4[3]));
    }
    // ---- defer-max guard: cross-lane reduce + rescale only on growth > 8 ----
    float g = fmaxf(lmax[0] - m[0], lmax[1] - m[1]);
    if (!__all(g <= 8.0f)) {
#pragma unroll
      for (int f = 0; f < 2; ++f) {
        float mxl = fmaxf(lmax[f], __shfl_xor(lmax[f], 16));
        mxl = fmaxf(mxl, __shfl_xor(mxl, 32));
        float mn = fmaxf(m[f], mxl);
        float al = exp2f(m[f] - mn);
        m[f] = mn;
        l[f] *= al;
        f32x4 av;
#pragma unroll
        for (int j = 0; j < 4; ++j) av[j] = __shfl(al, (lh << 2) + j);
#pragma unroll
        for (int nf = 0; nf < 4; ++nf) o[f][nf] *= av;
      }
    }
    // ---- exp2 + LANE-PARTIAL sum (no shuffles) + in-register P pack ----
    bf16x8 pa[2][2];
#pragma unroll
    for (int f = 0; f < 2; ++f) {
      f32x4 rs4 = {0.f, 0.f, 0.f, 0.f};
#pragma unroll
      for (int nf = 0; nf < 4; ++nf) {
#pragma unroll
        for (int j = 0; j < 4; ++j)
          sacc[f][nf][j] = exp2f(sacc[f][nf][j] - m[f]);
        rs4 += sacc[f][nf];
      }
      l[f] += (rs4[0] + rs4[1]) + (rs4[2] + rs4[3]);   // lane-partial
#pragma unroll
      for (int kk = 0; kk < 2; ++kk) {
        u32x4 w;
        w[0] = cvtpk(sacc[f][2 * kk][0], sacc[f][2 * kk][1]);
        w[1] = cvtpk(sacc[f][2 * kk][2], sacc[f][2 * kk][3]);
        w[2] = cvtpk(sacc[f][2 * kk + 1][0], sacc[f][2 * kk + 1][1]);
        w[3] = cvtpk(sacc[f][2 * kk + 1][2], sacc[f][2 * kk + 1][3]);
        pa[f][kk] = __builtin_bit_cast(bf16x8, w);
      }
    }
    // ---- PV ----
    const char* VsB = (const char*)&Vs[cur][0];
#pragma unroll
    for (int nf = 0; nf < 4; ++nf) {
#pragma unroll
      for (int kk = 0; kk < 2; ++kk) {
        bf16x8 vb = *(const bf16x8*)(VsB + (nf * 16 + lr) * 128 + ((kk * 64 + lh * 16) ^ swk));
        o[0][nf] = mfma16(pa[0][kk], vb, o[0][nf]);
        o[1][nf] = mfma16(pa[1][kk], vb, o[1][nf]);
      }
    }
    __syncthreads();   // drains staging vmcnt + protects buffer flip
    cur ^= 1;
  }

  // complete the row-sums: combine the 4 lane-partials of each row (once per chunk)
#pragma unroll
  for (int f = 0; f < 2; ++f) {
    l[f] += __shfl_xor(l[f], 16);
    l[f] += __shfl_xor(l[f], 32);
  }

  if (qt < 4) {
    // single-chunk q-tile: write normalized output directly to Ob (skip combine).
    // l[f] is lane-local to q-row lr; o[f][nf][j] lives at row lh*4+j -> transpose.
#pragma unroll
    for (int f = 0; f < 2; ++f) {
      f32x4 inv4;
#pragma unroll
      for (int j = 0; j < 4; ++j)
        inv4[j] = 1.0f / __shfl(l[f], (lh << 2) + j);
#pragma unroll
      for (int nf = 0; nf < 4; ++nf) {
        int col = h * 64 + nf * 16 + lr;
#pragma unroll
        for (int j = 0; j < 4; ++j) {
          int rloc = wid * 32 + f * 16 + (lh << 2) + j;
          Ob[((size_t)(b * S_LEN) + q0 + rloc) * HID + col] = (bf16)(o[f][nf][j] * inv4[j]);
        }
      }
    }
    return;
  }

  // epilogue: write unnormalized partial O (bf16) + per-row (m, l)
  size_t pbase = ((size_t)bh * NCHUNK + c) * (128 * 64);
#pragma unroll
  for (int f = 0; f < 2; ++f)
#pragma unroll
    for (int nf = 0; nf < 4; ++nf) {
      int col = nf * 16 + lr;
#pragma unroll
      for (int j = 0; j < 4; ++j) {
        int rloc = wid * 32 + f * 16 + (lh << 2) + j;
        Opart[pbase + (size_t)rloc * 64 + col] = (bf16)o[f][nf][j];
      }
    }
  if (lane < 16) {
    size_t mbase = ((size_t)bh * NCHUNK + c) * 128;
#pragma unroll
    for (int f = 0; f < 2; ++f) {
      int rloc = wid * 32 + f * 16 + lane;
      Oml[(mbase + rloc) * 2]     = m[f];
      Oml[(mbase + rloc) * 2 + 1] = l[f];
    }
  }
}

// ---------------- combine partials (qt >= 4 only; m in log2 domain) ----------------
__global__ __launch_bounds__(256) void combine_kernel(const bf16* __restrict__ Opart,
                                                      const float* __restrict__ Oml,
                                                      bf16* __restrict__ Ob) {
  int blk = blockIdx.x;            // bh*12 + (qt-4)
  int qt = 4 + blk % 12, bh = blk / 12;
  int h = bh % NHEADS, b = bh / NHEADS;
  int a = qt >> 2, bb = qt & 3;
  int nch = a + 1;
  int coff = (a + 1) * (2 * a + bb);
  int t = threadIdx.x;
  int row = t >> 1, cg = t & 1;    // 32 cols per thread

  float M = -__builtin_inff();
  for (int i = 0; i < nch; ++i)
    M = fmaxf(M, Oml[(((size_t)bh * NCHUNK + coff + i) * 128 + row) * 2]);
  float L = 0.f;
  for (int i = 0; i < nch; ++i) {
    size_t mb = (((size_t)bh * NCHUNK + coff + i) * 128 + row) * 2;
    L += exp2f(Oml[mb] - M) * Oml[mb + 1];
  }
  float acc[32];
#pragma unroll
  for (int k = 0; k < 32; ++k) acc[k] = 0.f;
  for (int i = 0; i < nch; ++i) {
    size_t mb = (((size_t)bh * NCHUNK + coff + i) * 128 + row) * 2;
    float w = exp2f(Oml[mb] - M);
    const bf16* src = Opart + (((size_t)bh * NCHUNK + coff + i) * 128 + row) * 64 + cg * 32;
#pragma unroll
    for (int v = 0; v < 4; ++v) {
      bf16x8 x = *reinterpret_cast<const bf16x8*>(src + v * 8);
#pragma unroll
      for (int k = 0; k < 8; ++k) acc[v * 8 + k] += w * (float)x[k];
    }
  }
  float inv = 1.0f / L;
  bf16* dst = Ob + ((size_t)(b * S_LEN) + qt * 128 + row) * HID + h * 64 + cg * 32;
#pragma unroll
  for (int v = 0; v < 4; ++v) {
    bf16x8 r;
#pragma unroll
    for (int k = 0; k < 8; ++k) r[k] = (bf16)(acc[v * 8 + k] * inv);
    *reinterpret_cast<bf16x8*>(dst + v * 8) = r;
  }
}

// ---------------- launch ----------------
extern "C" void kernel_launch(void* const* d_in, const int* in_sizes, int n_in,
                              void* d_out, int out_size, void* d_ws, size_t ws_size,
                              hipStream_t stream) {
  (void)in_sizes; (void)n_in; (void)out_size; (void)ws_size;
  const float* X  = (const float*)d_in[0];
  const float* Wq = (const float*)d_in[2];
  const float* bq = (const float*)d_in[3];
  const float* Wk = (const float*)d_in[4];
  const float* bk = (const float*)d_in[5];
  const float* Wv = (const float*)d_in[6];
  const float* bv = (const float*)d_in[7];
  const float* Wo = (const float*)d_in[8];
  float* OUT = (float*)d_out;

  char* ws = (char*)d_ws;
  bf16*  Xb    = (bf16*)(ws);                 // 4096*896*2  = 7,340,032
  bf16*  WqkvT = (bf16*)(ws + 7340032);       // 1152*896*2  = 2,064,384
  bf16*  WoT   = (bf16*)(ws + 9404416);       // 896*896*2   = 1,605,632
  float* biasq = (float*)(ws + 11010048);     // 1152*4
  bf16*  Opart = (bf16*)(ws + 11014656);      // 28*40*128*64*2 = 18,350,080
  float* trig  = (float*)(ws + 29364736);     // 2048*64*4 = 524,288 (ends 29,889,024)
  bf16*  Qbuf  = (bf16*)(ws + 29889024);      // 4096*896*2
  bf16*  Kbuf  = (bf16*)(ws + 37229056);      // 2*2*2048*64*2
  bf16*  Vbuf  = (bf16*)(ws + 38277632);      // 2*2*64*2048*2  (ends 39,326,208)
  float* Oml   = (float*)(ws + 7340032);      // reuse WqkvT region after GEMM1 (1,146,880)
  bf16*  Obuf  = Xb;                          // reuse (Xb dead after GEMM1)

  prep_kernel<<<5637, 256, 0, stream>>>(X, Xb, Wq, Wk, Wv, Wo, WqkvT, WoT,
                                        bq, bk, bv, biasq, trig);
  gemm_qkv_kernel<<<576, 256, 0, stream>>>(Xb, WqkvT, biasq, trig,
                                           Qbuf, Kbuf, Vbuf);
  attn_kernel<<<28 * NCHUNK, 256, 0, stream>>>(Qbuf, Kbuf, Vbuf, Opart, Oml, Obuf);
  combine_kernel<<<28 * 12, 256, 0, stream>>>(Opart, Oml, Obuf);
  gemm_bt_kernel<<<448, 256, 0, stream>>>(Obuf, WoT, OUT, 4096, 896, 896);
}